// Round 4
// baseline (266.982 us; speedup 1.0000x reference)
//
#include <hip/hip_runtime.h>
#include <hip/hip_fp16.h>

#define N_NODES 100000
#define CAP 64   // fixed CSR slots per node; deg is Poisson(10), P(>64) ~ 1e-25

typedef _Float16 v4h __attribute__((ext_vector_type(4)));
typedef float    v4f __attribute__((ext_vector_type(4)));

// ---------------- CSR build ----------------

// True XCD id of the executing workgroup (HW-verified via s_getreg, m09).
// Needed because the per-XCD deg replicas are only XCD-atomic: two workgroups
// sharing a replica MUST share an L2.
__device__ __forceinline__ int xcc_id() {
    unsigned x;
    asm volatile("s_getreg_b32 %0, hwreg(HW_REG_XCC_ID)" : "=s"(x));
    return (int)(x & 7);
}

// count: per-XCD-privatized histogram. Device-scope atomicAdd is ~20 G/s
// (resolved past the 8 non-coherent L2s — R1/R3 floor ~49-60 us). A
// WORKGROUP-scope atomic on a global address executes as an RMW at the LOCAL
// L2 (atomics bypass L1), which is atomic w.r.t. every workgroup on the same
// XCD. With one deg replica per XCD (indexed by the true XCC_ID), that is all
// the atomicity the count needs -> 8 L2s do local-rate atomics in parallel.
// rank[e] = (xcc<<28) | local_rank. Runs ALONE (R2 lesson: nothing may
// co-reside with the atomic-hot phase). Last block preps fp16 W^T tables.
__global__ void k_count(const int* __restrict__ dst, int* __restrict__ deg8,
                        int* __restrict__ rank, int E,
                        const float* __restrict__ W0, const float* __restrict__ W1,
                        const float* __restrict__ W2,
                        __half* __restrict__ Wt0h, __half* __restrict__ Wt0l,
                        __half* __restrict__ Wt1, __half* __restrict__ Wt2) {
    if (blockIdx.x == gridDim.x - 1) {
        // Wt[c][k] = W[k][c]; trivial next to the 1M-atomic count. W0 gets a
        // hi+lo split so layer 0 keeps near-fp32 precision.
        for (int i = threadIdx.x; i < 4096; i += 256) {
            int k = i >> 6, c = i & 63;
            float w0 = W0[i];
            __half w0h = __float2half(w0);
            Wt0h[(c << 6) + k] = w0h;
            Wt0l[(c << 6) + k] = __float2half(w0 - __half2float(w0h));
            Wt1[(c << 6) + k] = __float2half(W1[i]);
            Wt2[(c << 6) + k] = __float2half(W2[i]);
        }
        return;
    }
    int xcc = xcc_id();
    int* mydeg = deg8 + (size_t)xcc * N_NODES;
    unsigned tag = (unsigned)xcc << 28;
    int i = blockIdx.x * 256 + threadIdx.x;
    int E4 = E >> 2;
    if (i < E4) {
        int4 d = ((const int4*)dst)[i];
        int4 r;
        r.x = (int)(tag | (unsigned)__hip_atomic_fetch_add(&mydeg[d.x], 1,
                     __ATOMIC_RELAXED, __HIP_MEMORY_SCOPE_WORKGROUP));
        r.y = (int)(tag | (unsigned)__hip_atomic_fetch_add(&mydeg[d.y], 1,
                     __ATOMIC_RELAXED, __HIP_MEMORY_SCOPE_WORKGROUP));
        r.z = (int)(tag | (unsigned)__hip_atomic_fetch_add(&mydeg[d.z], 1,
                     __ATOMIC_RELAXED, __HIP_MEMORY_SCOPE_WORKGROUP));
        r.w = (int)(tag | (unsigned)__hip_atomic_fetch_add(&mydeg[d.w], 1,
                     __ATOMIC_RELAXED, __HIP_MEMORY_SCOPE_WORKGROUP));
        ((int4*)rank)[i] = r;
    } else if (i == E4) {
        for (int k = E & ~3; k < E; k++)
            rank[k] = (int)(tag | (unsigned)__hip_atomic_fetch_add(&mydeg[dst[k]], 1,
                             __ATOMIC_RELAXED, __HIP_MEMORY_SCOPE_WORKGROUP));
    }
}

// offs[xcc][node] = exclusive prefix of deg8 over xcc; deg[node] = total.
// N-parallel, ~7 MB traffic, ~3 us.
__global__ __launch_bounds__(256) void k_offs(const int* __restrict__ deg8,
                                              int* __restrict__ offs,
                                              int* __restrict__ deg, int n) {
    int i = blockIdx.x * 256 + threadIdx.x;
    if (i >= n) return;
    int run = 0;
#pragma unroll
    for (int x = 0; x < 8; x++) {
        int c = deg8[(size_t)x * n + i];
        offs[(size_t)x * n + i] = run;
        run += c;
    }
    deg[i] = run;
}

// phaseB: fill(all E, atomic-free scattered stores) || gemm0 (h'0 = (x@W0)*dinv).
// Disjoint pipes: fill = fire-and-forget write path (+ one L3-resident offs
// read per edge to decode the per-XCD rank), gemm = read stream + MFMA.
// gemm: A = x hi/lo split, B = W0 hi/lo split -> near-fp32 product
// (xh*Wh + xl*Wh + xh*Wl; xl*Wl ~ 2^-22 rel). LDS 4.6 KB.
__global__ __launch_bounds__(256) void k_phaseB(const int* __restrict__ src,
                                                const int* __restrict__ dst,
                                                const int* __restrict__ rank,
                                                const int* __restrict__ offs,
                                                int* __restrict__ csr, int E, int FB,
                                                const float* __restrict__ x,
                                                const __half* __restrict__ Wth,
                                                const __half* __restrict__ Wtl,
                                                const int* __restrict__ deg,
                                                __half* __restrict__ outh) {
    __shared__ _Float16 xs_hi[16 * 68];   // stride 68: even bank spread for b64
    __shared__ _Float16 xs_lo[16 * 68];
    __shared__ float dsv[16];
    if ((int)blockIdx.x < FB) {
        int i = blockIdx.x * 256 + (int)threadIdx.x;
        int E4 = E >> 2;
        if (i < E4) {
            int4 d = ((const int4*)dst)[i];
            int4 s = ((const int4*)src)[i];
            int4 r = ((const int4*)rank)[i];
            int s0 = offs[(size_t)((unsigned)r.x >> 28) * N_NODES + d.x] + (r.x & 0x0FFFFFFF);
            int s1 = offs[(size_t)((unsigned)r.y >> 28) * N_NODES + d.y] + (r.y & 0x0FFFFFFF);
            int s2 = offs[(size_t)((unsigned)r.z >> 28) * N_NODES + d.z] + (r.z & 0x0FFFFFFF);
            int s3 = offs[(size_t)((unsigned)r.w >> 28) * N_NODES + d.w] + (r.w & 0x0FFFFFFF);
            if (s0 < CAP) csr[(d.x << 6) + s0] = s.x;
            if (s1 < CAP) csr[(d.y << 6) + s1] = s.y;
            if (s2 < CAP) csr[(d.z << 6) + s2] = s.z;
            if (s3 < CAP) csr[(d.w << 6) + s3] = s.w;
        } else if (i == E4) {
            for (int k = E & ~3; k < E; k++) {
                unsigned rr = (unsigned)rank[k];
                int sl = offs[(size_t)(rr >> 28) * N_NODES + dst[k]] + (int)(rr & 0x0FFFFFFF);
                if (sl < CAP) csr[(dst[k] << 6) + sl] = src[k];
            }
        }
        return;
    }
    int bg = blockIdx.x - FB;
    int t = threadIdx.x;
    int rl = t >> 4, q = t & 15;
    int lane = t & 63;
    int w = t >> 6;
    int col = (w << 4) + (lane & 15);
    int g = lane >> 4;
    int node = bg * 16 + rl;

    // nt load: x is streamed once, don't evict csr/offs lines the fill needs
    v4f xv = __builtin_nontemporal_load((const v4f*)x + (size_t)bg * 256 + t);
    int dg = deg[node];
    float d_i = rsqrtf((float)(dg + 1));
    if (q == 0) dsv[rl] = d_i;

    const v4h* wth4 = (const v4h*)(Wth + ((size_t)col << 6));
    const v4h* wtl4 = (const v4h*)(Wtl + ((size_t)col << 6));
    v4h bfh[4], bfl[4];
#pragma unroll
    for (int s = 0; s < 4; s++) { bfh[s] = wth4[(s << 2) + g]; bfl[s] = wtl4[(s << 2) + g]; }

    v4h yh = {(_Float16)xv.x, (_Float16)xv.y, (_Float16)xv.z, (_Float16)xv.w};
    v4h yl = {(_Float16)(xv.x - (float)yh.x), (_Float16)(xv.y - (float)yh.y),
              (_Float16)(xv.z - (float)yh.z), (_Float16)(xv.w - (float)yh.w)};
    *(v4h*)&xs_hi[rl * 68 + (q << 2)] = yh;
    *(v4h*)&xs_lo[rl * 68 + (q << 2)] = yl;
    __syncthreads();

    v4f acc = {0.f, 0.f, 0.f, 0.f};
    int arow = lane & 15;
#pragma unroll
    for (int s = 0; s < 4; s++) {
        v4h al = *(const v4h*)&xs_lo[arow * 68 + (s << 4) + (g << 2)];
        v4h ah = *(const v4h*)&xs_hi[arow * 68 + (s << 4) + (g << 2)];
        acc = __builtin_amdgcn_mfma_f32_16x16x16f16(al, bfh[s], acc, 0, 0, 0);
        acc = __builtin_amdgcn_mfma_f32_16x16x16f16(ah, bfl[s], acc, 0, 0, 0);
        acc = __builtin_amdgcn_mfma_f32_16x16x16f16(ah, bfh[s], acc, 0, 0, 0);
    }
#pragma unroll
    for (int j = 0; j < 4; j++) {
        int r = (g << 2) + j;
        float v = acc[j] * dsv[r];
        outh[((size_t)(bg * 16 + r) << 6) + col] = __float2half(v);
    }
}

// ---------------- gather helpers ----------------

// fp16 pairwise add of two gathered uint2s: 2x v_pk_add_f16 instead of
// 8x cvt/add. Exactly ONE fp16 rounding per element -> rms error ~3e-4,
// within budget (R3 passed at 4.88e-4 total).
__device__ __forceinline__ uint2 padd(uint2 u, uint2 v) {
    __half2 a0 = *(__half2*)&u.x, a1 = *(__half2*)&u.y;
    __half2 b0 = *(__half2*)&v.x, b1 = *(__half2*)&v.y;
    __half2 c0 = __hadd2(a0, b0), c1 = __hadd2(a1, b1);
    uint2 r;
    r.x = *(unsigned int*)&c0;
    r.y = *(unsigned int*)&c1;
    return r;
}

// v4f accumulate (vector op so LLVM can form v_pk_add_f32)
__device__ __forceinline__ void acc_h(v4f& a, uint2 v) {
    __half2 h0 = *(__half2*)&v.x;
    __half2 h1 = *(__half2*)&v.y;
    float2 f0 = __half22float2(h0);
    float2 f1 = __half22float2(h1);
    v4f f = {f0.x, f0.y, f1.x, f1.y};
    a = a + f;
}

// a = h'[node] + sum_j h'[j]; fp32 master acc, one fp16 pairing level.
// Caller pre-loads ia=c4[0], ib=c4[1] BEFORE the deg load so the
// deg->idx->gather chain collapses to one hop. Loop maintains ia=c4[e/4],
// ib=c4[e/4+1]; prefetched entries may read up to 28 B past the node's row
// (in-allocation) and are only USED when the count checks validate them.
__device__ __forceinline__ v4f gather_acc(const uint2* __restrict__ h,
                                          const int* __restrict__ csr,
                                          int4 ia, int4 ib,
                                          int node, int q, int cnt) {
    const int4* c4 = (const int4*)(csr + (node << 6));
    v4f A0 = {0,0,0,0}, A1 = {0,0,0,0}, A2 = {0,0,0,0}, A3 = {0,0,0,0};
    acc_h(A0, h[(size_t)node * 16 + q]);  // self loop (fp32 path, exact)
    int e = 0;
    for (; e + 8 <= cnt; ) {
        uint2 v0 = h[(size_t)ia.x * 16 + q];
        uint2 v1 = h[(size_t)ia.y * 16 + q];
        uint2 v2 = h[(size_t)ia.z * 16 + q];
        uint2 v3 = h[(size_t)ia.w * 16 + q];
        uint2 v4 = h[(size_t)ib.x * 16 + q];
        uint2 v5 = h[(size_t)ib.y * 16 + q];
        uint2 v6 = h[(size_t)ib.z * 16 + q];
        uint2 v7 = h[(size_t)ib.w * 16 + q];
        e += 8;
        ia = c4[e >> 2];            // prefetch overlaps the accumulate VALU below
        ib = c4[(e >> 2) + 1];
        uint2 p0 = padd(v0, v1);
        uint2 p1 = padd(v2, v3);
        uint2 p2 = padd(v4, v5);
        uint2 p3 = padd(v6, v7);
        acc_h(A0, p0); acc_h(A1, p1); acc_h(A2, p2); acc_h(A3, p3);
    }
    if (e + 4 <= cnt) {
        uint2 v0 = h[(size_t)ia.x * 16 + q];
        uint2 v1 = h[(size_t)ia.y * 16 + q];
        uint2 v2 = h[(size_t)ia.z * 16 + q];
        uint2 v3 = h[(size_t)ia.w * 16 + q];
        uint2 p0 = padd(v0, v1);
        uint2 p1 = padd(v2, v3);
        acc_h(A1, p0); acc_h(A2, p1);
        e += 4;
        ia = ib;                    // keep invariant ia = c4[e/4]
    }
    int rem = cnt - e;              // 0..3, one masked parallel iteration (fp32)
    if (rem > 0) {
        int j0 = ia.x;              // slot e < cnt -> valid
        int j1 = (rem > 1) ? ia.y : j0;
        int j2 = (rem > 2) ? ia.z : j0;
        uint2 v0 = h[(size_t)j0 * 16 + q];
        uint2 v1 = h[(size_t)j1 * 16 + q];
        uint2 v2 = h[(size_t)j2 * 16 + q];
        acc_h(A1, v0);
        if (rem > 1) acc_h(A2, v1);
        if (rem > 2) acc_h(A3, v2);
    }
    return (A0 + A1) + (A2 + A3);
}

// Fused interior layer: y = relu(dinv_i*(gather h'_l) + b_l) -> h'_{l+1} = (y @ W_{l+1})*dinv_i
// GEMM on MFMA: A = y split hi/lo fp16 (near-fp32 precision), B = Wt fp16 from
// global (8 KB, L2-hot). Per wave: 16x16 out tile, 4 K-steps x {lo,hi} = 8 MFMAs.
__global__ __launch_bounds__(256) void k_gather_gemm(const uint2* __restrict__ h,
                                                     const int* __restrict__ csr,
                                                     const int* __restrict__ deg,
                                                     const float* __restrict__ bias,
                                                     const __half* __restrict__ Wt,
                                                     __half* __restrict__ outh, int n) {
    // row stride 68 halves (34 dwords ≡ 2 mod 32): 16 rows x b64 touch all 32
    // banks evenly -> min-cycle LDS access for A-fragment reads.
    __shared__ _Float16 xs_hi[16 * 68];
    __shared__ _Float16 xs_lo[16 * 68];
    __shared__ float dsv[16];
    (void)n;
    int t = threadIdx.x;
    int rl = t >> 4, q = t & 15;
    int node = blockIdx.x * 16 + rl;
    int lane = t & 63;
    int w = t >> 6;                  // wave id 0..3 -> out-col tile
    int col = (w << 4) + (lane & 15);
    int g = lane >> 4;               // k-subgroup within fragment

    const int4* c4 = (const int4*)(csr + (node << 6));
    int4 ia0 = c4[0];                // idx hoist: overlaps the deg load
    int4 ib0 = c4[1];
    int dg = deg[node];
    int cnt = min(dg, CAP);
    float d_i = rsqrtf((float)(dg + 1));
    if (q == 0) dsv[rl] = d_i;
    float4 b = ((const float4*)bias)[q];

    v4f a = gather_acc(h, csr, ia0, ib0, node, q, cnt);

    // B fragments (lane: B[k][j], j=lane&15 -> col, k=16s+4g..+3): issue now,
    // latency hides under relu/convert/LDS-write/barrier.
    const v4h* wt4 = (const v4h*)(Wt + ((size_t)col << 6));
    v4h bf[4];
#pragma unroll
    for (int s = 0; s < 4; s++) bf[s] = wt4[(s << 2) + g];

    float y0 = fmaxf(fmaf(a.x, d_i, b.x), 0.f);
    float y1 = fmaxf(fmaf(a.y, d_i, b.y), 0.f);
    float y2 = fmaxf(fmaf(a.z, d_i, b.z), 0.f);
    float y3 = fmaxf(fmaf(a.w, d_i, b.w), 0.f);
    v4h yh = {(_Float16)y0, (_Float16)y1, (_Float16)y2, (_Float16)y3};
    v4h yl = {(_Float16)(y0 - (float)yh.x), (_Float16)(y1 - (float)yh.y),
              (_Float16)(y2 - (float)yh.z), (_Float16)(y3 - (float)yh.w)};
    *(v4h*)&xs_hi[rl * 68 + (q << 2)] = yh;
    *(v4h*)&xs_lo[rl * 68 + (q << 2)] = yl;
    __syncthreads();

    v4f acc = {0.f, 0.f, 0.f, 0.f};
    int arow = lane & 15;            // A: row = lane&15, k = 16s + 4g + 0..3
#pragma unroll
    for (int s = 0; s < 4; s++) {
        v4h al = *(const v4h*)&xs_lo[arow * 68 + (s << 4) + (g << 2)];
        v4h ah = *(const v4h*)&xs_hi[arow * 68 + (s << 4) + (g << 2)];
        acc = __builtin_amdgcn_mfma_f32_16x16x16f16(al, bf[s], acc, 0, 0, 0);
        acc = __builtin_amdgcn_mfma_f32_16x16x16f16(ah, bf[s], acc, 0, 0, 0);
    }

    // D: col = lane&15 (-> global col), row = 4*(lane>>4) + j. Scale by the
    // OUTPUT row's dinv (from LDS, written pre-barrier), store fp16 scalar
    // (4x 32 B contiguous segments per store instr -- write path, cheap).
#pragma unroll
    for (int j = 0; j < 4; j++) {
        int r = (g << 2) + j;
        float v = acc[j] * dsv[r];
        outh[((size_t)(blockIdx.x * 16 + r) << 6) + col] = __float2half(v);
    }
}

// Final gather: out = relu(dinv_i*(gather h'_2) + b2), fp32 out.
__global__ __launch_bounds__(256) void k_gather(const uint2* __restrict__ h,
                                                const int* __restrict__ csr,
                                                const int* __restrict__ deg,
                                                const float* __restrict__ bias,
                                                float* __restrict__ out, int n) {
    int t = threadIdx.x;
    int node = blockIdx.x * 16 + (t >> 4);
    int q = t & 15;
    if (node >= n) return;
    const int4* c4 = (const int4*)(csr + (node << 6));
    int4 ia0 = c4[0];                // idx hoist (see gather_acc)
    int4 ib0 = c4[1];
    int dg = deg[node];
    int cnt = min(dg, CAP);
    float d = rsqrtf((float)(dg + 1));
    v4f a = gather_acc(h, csr, ia0, ib0, node, q, cnt);
    float4 b = ((const float4*)bias)[q];
    float4 r;
    r.x = fmaxf(fmaf(a.x, d, b.x), 0.f);
    r.y = fmaxf(fmaf(a.y, d, b.y), 0.f);
    r.z = fmaxf(fmaf(a.z, d, b.z), 0.f);
    r.w = fmaxf(fmaf(a.w, d, b.w), 0.f);
    ((float4*)out)[(size_t)node * 16 + q] = r;
}

// ---------------- launch ----------------

extern "C" void kernel_launch(void* const* d_in, const int* in_sizes, int n_in,
                              void* d_out, int out_size, void* d_ws, size_t ws_size,
                              hipStream_t stream) {
    const float* x  = (const float*)d_in[0];
    const int*   ei = (const int*)d_in[1];
    const float* W0 = (const float*)d_in[2];
    const float* b0 = (const float*)d_in[3];
    const float* W1 = (const float*)d_in[4];
    const float* b1 = (const float*)d_in[5];
    const float* W2 = (const float*)d_in[6];
    const float* b2 = (const float*)d_in[7];
    float* out = (float*)d_out;

    const int N = N_NODES;
    int E = in_sizes[1] / 2;
    const int* src = ei;
    const int* dst = ei + E;

    char* p = (char*)d_ws;
    auto alloc = [&](size_t bytes) -> void* {
        void* r = (void*)p;
        p += (bytes + 511) & ~(size_t)511;
        return r;
    };
    int*    deg8 = (int*)alloc((size_t)8 * N * 4);       // per-XCD count replicas
    int*    offs = (int*)alloc((size_t)8 * N * 4);       // exclusive scan over XCDs
    int*    deg  = (int*)alloc((size_t)N * 4);
    int*    rank = (int*)alloc((size_t)E * 4 + 1024);    // (xcc<<28)|local_rank
    int*    csr  = (int*)alloc((size_t)N * CAP * 4);     // 25.6 MB fixed slots
    uint2*  hA   = (uint2*)alloc((size_t)N * 64 * 2);    // fp16 h', 12.8 MB
    uint2*  hB   = (uint2*)alloc((size_t)N * 64 * 2);
    __half* Wt0h = (__half*)alloc(4096 * 2);             // fp16 W^T, MFMA B operands
    __half* Wt0l = (__half*)alloc(4096 * 2);             // (W0 split hi+lo)
    __half* Wt1  = (__half*)alloc(4096 * 2);
    __half* Wt2  = (__half*)alloc(4096 * 2);

    const int GEMM_B = N / 16;               // 6250
    const int GATH_B = (N + 15) / 16;        // 6250
    const int EB = (E / 4 + 255) / 256 + 1;  // count/fill blocks (+1 remainder lane)
    const int OFFS_B = (N + 255) / 256;

    (void)hipMemsetAsync(deg8, 0, (size_t)8 * N * 4, stream);
    // count alone (atomic-hot phase tolerates nothing co-resident), XCD-local
    // L2 atomics via per-XCD replicas; +1 block preps Wt tables
    k_count<<<EB + 1, 256, 0, stream>>>(dst, deg8, rank, E,
                                        W0, W1, W2, Wt0h, Wt0l, Wt1, Wt2);
    // per-node exclusive scan over the 8 replicas -> offs, total deg
    k_offs<<<OFFS_B, 256, 0, stream>>>(deg8, offs, deg, N);
    // fill (scattered writes, offs-decoded slots) || gemm0 (MFMA + read stream)
    k_phaseB<<<EB + GEMM_B, 256, 0, stream>>>(src, dst, rank, offs, csr, E, EB,
                                              x, Wt0h, Wt0l, deg, (__half*)hA);
    // fused: gather(h'_0) -> y0 -> @W1 (MFMA) -> h'_1
    k_gather_gemm<<<GATH_B, 256, 0, stream>>>(hA, csr, deg, b0, Wt1, (__half*)hB, N);
    // fused: gather(h'_1) -> y1 -> @W2 (MFMA) -> h'_2
    k_gather_gemm<<<GATH_B, 256, 0, stream>>>(hB, csr, deg, b1, Wt2, (__half*)hA, N);
    // final gather -> out (fp32)
    k_gather<<<GATH_B, 256, 0, stream>>>(hA, csr, deg, b2, out, N);
}

// Round 5
// 257.903 us; speedup vs baseline: 1.0352x; 1.0352x over previous
//
#include <hip/hip_runtime.h>
#include <hip/hip_fp16.h>

#define N_NODES 100000
#define CAP 64   // fixed CSR slots per node; deg is Poisson(10), P(>64) ~ 1e-25

typedef _Float16 v4h __attribute__((ext_vector_type(4)));
typedef float    v4f __attribute__((ext_vector_type(4)));

// ---------------- CSR build ----------------

// count: rank[e] = atomicAdd(deg[dst[e]], 1). Runs ALONE with COALESCED rank
// stores only. Measured walls: fusing the csr scatter in halved atomic rate
// (R2, 20->11 G/s); per-XCD replicas + workgroup-scope atomics changed NOTHING
// (R4: scope is page/memory-side enforced on MI355X, not instruction
// enforced). ~1M returning dev-atomics at 17-20 G/s = 50-60 us structural
// floor for this phase. Last block preps fp16 W^T tables (MFMA B operands);
// W0 gets a hi+lo split so layer 0 keeps near-fp32 precision.
__global__ void k_count(const int* __restrict__ dst, int* __restrict__ deg,
                        int* __restrict__ rank, int E,
                        const float* __restrict__ W0, const float* __restrict__ W1,
                        const float* __restrict__ W2,
                        __half* __restrict__ Wt0h, __half* __restrict__ Wt0l,
                        __half* __restrict__ Wt1, __half* __restrict__ Wt2) {
    if (blockIdx.x == gridDim.x - 1) {
        // Wt[c][k] = W[k][c]; trivial next to the 1M-atomic count.
        for (int i = threadIdx.x; i < 4096; i += 256) {
            int k = i >> 6, c = i & 63;
            float w0 = W0[i];
            __half w0h = __float2half(w0);
            Wt0h[(c << 6) + k] = w0h;
            Wt0l[(c << 6) + k] = __float2half(w0 - __half2float(w0h));
            Wt1[(c << 6) + k] = __float2half(W1[i]);
            Wt2[(c << 6) + k] = __float2half(W2[i]);
        }
        return;
    }
    int i = blockIdx.x * 256 + threadIdx.x;
    int E4 = E >> 2;
    if (i < E4) {
        int4 d = ((const int4*)dst)[i];
        int4 r;
        r.x = atomicAdd(&deg[d.x], 1);
        r.y = atomicAdd(&deg[d.y], 1);
        r.z = atomicAdd(&deg[d.z], 1);
        r.w = atomicAdd(&deg[d.w], 1);
        ((int4*)rank)[i] = r;
    } else if (i == E4) {
        for (int k = E & ~3; k < E; k++)
            rank[k] = atomicAdd(&deg[dst[k]], 1);
    }
}

// phaseB: fill(all E, atomic-free scattered stores) || gemm0 (h'0 = (x@W0)*dinv).
// Disjoint pipes: fill = fire-and-forget write path, gemm = read stream + MFMA.
// gemm: A = x hi/lo split, B = W0 hi/lo split -> near-fp32 product
// (xh*Wh + xl*Wh + xh*Wl; xl*Wl ~ 2^-22 rel). LDS 4.6 KB.
__global__ __launch_bounds__(256) void k_phaseB(const int* __restrict__ src,
                                                const int* __restrict__ dst,
                                                const int* __restrict__ rank,
                                                int* __restrict__ csr, int E, int FB,
                                                const float* __restrict__ x,
                                                const __half* __restrict__ Wth,
                                                const __half* __restrict__ Wtl,
                                                const int* __restrict__ deg,
                                                __half* __restrict__ outh) {
    __shared__ _Float16 xs_hi[16 * 68];   // stride 68: even bank spread for b64
    __shared__ _Float16 xs_lo[16 * 68];
    __shared__ float dsv[16];
    if ((int)blockIdx.x < FB) {
        int i = blockIdx.x * 256 + (int)threadIdx.x;
        int E4 = E >> 2;
        if (i < E4) {
            int4 d = ((const int4*)dst)[i];
            int4 s = ((const int4*)src)[i];
            int4 r = ((const int4*)rank)[i];
            if (r.x < CAP) csr[(d.x << 6) + r.x] = s.x;
            if (r.y < CAP) csr[(d.y << 6) + r.y] = s.y;
            if (r.z < CAP) csr[(d.z << 6) + r.z] = s.z;
            if (r.w < CAP) csr[(d.w << 6) + r.w] = s.w;
        } else if (i == E4) {
            for (int k = E & ~3; k < E; k++) {
                int rr = rank[k];
                if (rr < CAP) csr[(dst[k] << 6) + rr] = src[k];
            }
        }
        return;
    }
    int bg = blockIdx.x - FB;
    int t = threadIdx.x;
    int rl = t >> 4, q = t & 15;
    int lane = t & 63;
    int w = t >> 6;
    int col = (w << 4) + (lane & 15);
    int g = lane >> 4;
    int node = bg * 16 + rl;

    // nt load: x is streamed once, don't evict csr/deg lines the fill needs
    v4f xv = __builtin_nontemporal_load((const v4f*)x + (size_t)bg * 256 + t);
    int dg = deg[node];
    float d_i = rsqrtf((float)(dg + 1));
    if (q == 0) dsv[rl] = d_i;

    const v4h* wth4 = (const v4h*)(Wth + ((size_t)col << 6));
    const v4h* wtl4 = (const v4h*)(Wtl + ((size_t)col << 6));
    v4h bfh[4], bfl[4];
#pragma unroll
    for (int s = 0; s < 4; s++) { bfh[s] = wth4[(s << 2) + g]; bfl[s] = wtl4[(s << 2) + g]; }

    v4h yh = {(_Float16)xv.x, (_Float16)xv.y, (_Float16)xv.z, (_Float16)xv.w};
    v4h yl = {(_Float16)(xv.x - (float)yh.x), (_Float16)(xv.y - (float)yh.y),
              (_Float16)(xv.z - (float)yh.z), (_Float16)(xv.w - (float)yh.w)};
    *(v4h*)&xs_hi[rl * 68 + (q << 2)] = yh;
    *(v4h*)&xs_lo[rl * 68 + (q << 2)] = yl;
    __syncthreads();

    v4f acc = {0.f, 0.f, 0.f, 0.f};
    int arow = lane & 15;
#pragma unroll
    for (int s = 0; s < 4; s++) {
        v4h al = *(const v4h*)&xs_lo[arow * 68 + (s << 4) + (g << 2)];
        v4h ah = *(const v4h*)&xs_hi[arow * 68 + (s << 4) + (g << 2)];
        acc = __builtin_amdgcn_mfma_f32_16x16x16f16(al, bfh[s], acc, 0, 0, 0);
        acc = __builtin_amdgcn_mfma_f32_16x16x16f16(ah, bfl[s], acc, 0, 0, 0);
        acc = __builtin_amdgcn_mfma_f32_16x16x16f16(ah, bfh[s], acc, 0, 0, 0);
    }
#pragma unroll
    for (int j = 0; j < 4; j++) {
        int r = (g << 2) + j;
        float v = acc[j] * dsv[r];
        outh[((size_t)(bg * 16 + r) << 6) + col] = __float2half(v);
    }
}

// ---------------- gather helpers (16B-granular) ----------------

// fp16 pairwise add of two gathered uint4s (8 halves): 4x v_pk_add_f16.
// Exactly ONE fp16 rounding per element (same tree as R3, which passed at
// 4.88e-4 total).
__device__ __forceinline__ uint4 padd4(uint4 u, uint4 v) {
    __half2* a = (__half2*)&u;
    __half2* b = (__half2*)&v;
    uint4 r;
    __half2* c = (__half2*)&r;
#pragma unroll
    for (int k = 0; k < 4; k++) c[k] = __hadd2(a[k], b[k]);
    return r;
}

// fp32 accumulate of 8 halves into two v4f
__device__ __forceinline__ void acc_h4(v4f& A, v4f& B, uint4 v) {
    __half2* h = (__half2*)&v;
    float2 f0 = __half22float2(h[0]);
    float2 f1 = __half22float2(h[1]);
    float2 f2 = __half22float2(h[2]);
    float2 f3 = __half22float2(h[3]);
    v4f fa = {f0.x, f0.y, f1.x, f1.y};
    v4f fb = {f2.x, f2.y, f3.x, f3.y};
    A = A + fa;
    B = B + fb;
}

// yA/yB = 8 columns of h'[node] + sum_j h'[j]; fp32 master acc, one fp16
// pairing level. 16B loads (uint4, 8 lanes/node): half the VMEM instructions
// and 2x bytes per outstanding request vs the old uint2 path — the gather is
// latency-throughput-bound (R0: 3.1 TB/s effective vs ~15-20 us mixed-tier
// floor), so bytes-in-flight is the lever. Caller pre-loads ia=c4[0], ib=c4[1]
// BEFORE the deg load so the deg->idx->gather chain collapses to one hop.
// Prefetched idx entries may read up to 28 B past the node's row
// (in-allocation) and are only USED when the count checks validate them.
__device__ __forceinline__ void gather_acc4(const uint4* __restrict__ h4,
                                            const int* __restrict__ csr,
                                            int4 ia, int4 ib,
                                            int node, int qq, int cnt,
                                            v4f& yA, v4f& yB) {
    const int4* c4 = (const int4*)(csr + (node << 6));
    v4f A0 = {0,0,0,0}, A1 = {0,0,0,0}, A2 = {0,0,0,0}, A3 = {0,0,0,0};
    v4f B0 = {0,0,0,0}, B1 = {0,0,0,0}, B2 = {0,0,0,0}, B3 = {0,0,0,0};
    acc_h4(A0, B0, h4[(size_t)node * 8 + qq]);  // self loop (fp32 path)
    int e = 0;
    for (; e + 8 <= cnt; ) {
        uint4 v0 = h4[(size_t)ia.x * 8 + qq];
        uint4 v1 = h4[(size_t)ia.y * 8 + qq];
        uint4 v2 = h4[(size_t)ia.z * 8 + qq];
        uint4 v3 = h4[(size_t)ia.w * 8 + qq];
        uint4 v4 = h4[(size_t)ib.x * 8 + qq];
        uint4 v5 = h4[(size_t)ib.y * 8 + qq];
        uint4 v6 = h4[(size_t)ib.z * 8 + qq];
        uint4 v7 = h4[(size_t)ib.w * 8 + qq];
        e += 8;
        ia = c4[e >> 2];            // prefetch overlaps the accumulate VALU below
        ib = c4[(e >> 2) + 1];
        uint4 p0 = padd4(v0, v1);
        uint4 p1 = padd4(v2, v3);
        uint4 p2 = padd4(v4, v5);
        uint4 p3 = padd4(v6, v7);
        acc_h4(A0, B0, p0); acc_h4(A1, B1, p1);
        acc_h4(A2, B2, p2); acc_h4(A3, B3, p3);
    }
    if (e + 4 <= cnt) {
        uint4 v0 = h4[(size_t)ia.x * 8 + qq];
        uint4 v1 = h4[(size_t)ia.y * 8 + qq];
        uint4 v2 = h4[(size_t)ia.z * 8 + qq];
        uint4 v3 = h4[(size_t)ia.w * 8 + qq];
        uint4 p0 = padd4(v0, v1);
        uint4 p1 = padd4(v2, v3);
        acc_h4(A1, B1, p0); acc_h4(A2, B2, p1);
        e += 4;
        ia = ib;                    // keep invariant ia = c4[e/4]
    }
    int rem = cnt - e;              // 0..3, one masked parallel iteration (fp32)
    if (rem > 0) {
        int j0 = ia.x;              // slot e < cnt -> valid
        int j1 = (rem > 1) ? ia.y : j0;
        int j2 = (rem > 2) ? ia.z : j0;
        uint4 v0 = h4[(size_t)j0 * 8 + qq];
        uint4 v1 = h4[(size_t)j1 * 8 + qq];
        uint4 v2 = h4[(size_t)j2 * 8 + qq];
        acc_h4(A1, B1, v0);
        if (rem > 1) acc_h4(A2, B2, v1);
        if (rem > 2) acc_h4(A3, B3, v2);
    }
    yA = (A0 + A1) + (A2 + A3);
    yB = (B0 + B1) + (B2 + B3);
}

// Fused interior layer, 32 nodes/block (8 lanes x 16B per node):
// y = relu(dinv_i*(gather h'_l) + b_l) -> h'_{l+1} = (y @ W_{l+1})*dinv_i.
// GEMM on MFMA: A = y split hi/lo fp16, B = Wt fp16 from global (L2-hot).
// Per wave: two 16x16 out tiles (rows 0-15 / 16-31), 16 MFMAs.
__global__ __launch_bounds__(256) void k_gather_gemm(const uint4* __restrict__ h4,
                                                     const int* __restrict__ csr,
                                                     const int* __restrict__ deg,
                                                     const float* __restrict__ bias,
                                                     const __half* __restrict__ Wt,
                                                     __half* __restrict__ outh, int n) {
    // row stride 68 halves (34 dwords ≡ 2 mod 32): b64 reads spread all banks
    __shared__ _Float16 xs_hi[32 * 68];
    __shared__ _Float16 xs_lo[32 * 68];
    __shared__ float dsv[32];
    (void)n;
    int t = threadIdx.x;
    int nl = t >> 3, qq = t & 7;     // 32 nodes/block, 8 lanes/node
    int node = blockIdx.x * 32 + nl;
    int lane = t & 63;
    int w = t >> 6;                  // wave id 0..3 -> out-col tile
    int col = (w << 4) + (lane & 15);
    int g = lane >> 4;               // k-subgroup within fragment

    const int4* c4 = (const int4*)(csr + (node << 6));
    int4 ia0 = c4[0];                // idx hoist: overlaps the deg load
    int4 ib0 = c4[1];
    int dg = deg[node];
    int cnt = min(dg, CAP);
    float d_i = rsqrtf((float)(dg + 1));
    if (qq == 0) dsv[nl] = d_i;
    float4 bA = ((const float4*)bias)[qq * 2 + 0];
    float4 bB = ((const float4*)bias)[qq * 2 + 1];

    v4f aA, aB;
    gather_acc4(h4, csr, ia0, ib0, node, qq, cnt, aA, aB);

    // B fragments (lane: B[k][j], j -> col, k=16s+4g..+3): issue now, latency
    // hides under relu/convert/LDS-write/barrier.
    const v4h* wt4 = (const v4h*)(Wt + ((size_t)col << 6));
    v4h bf[4];
#pragma unroll
    for (int s = 0; s < 4; s++) bf[s] = wt4[(s << 2) + g];

    float y0 = fmaxf(fmaf(aA.x, d_i, bA.x), 0.f);
    float y1 = fmaxf(fmaf(aA.y, d_i, bA.y), 0.f);
    float y2 = fmaxf(fmaf(aA.z, d_i, bA.z), 0.f);
    float y3 = fmaxf(fmaf(aA.w, d_i, bA.w), 0.f);
    float y4 = fmaxf(fmaf(aB.x, d_i, bB.x), 0.f);
    float y5 = fmaxf(fmaf(aB.y, d_i, bB.y), 0.f);
    float y6 = fmaxf(fmaf(aB.z, d_i, bB.z), 0.f);
    float y7 = fmaxf(fmaf(aB.w, d_i, bB.w), 0.f);
    v4h yhA = {(_Float16)y0, (_Float16)y1, (_Float16)y2, (_Float16)y3};
    v4h ylA = {(_Float16)(y0 - (float)yhA.x), (_Float16)(y1 - (float)yhA.y),
               (_Float16)(y2 - (float)yhA.z), (_Float16)(y3 - (float)yhA.w)};
    v4h yhB = {(_Float16)y4, (_Float16)y5, (_Float16)y6, (_Float16)y7};
    v4h ylB = {(_Float16)(y4 - (float)yhB.x), (_Float16)(y5 - (float)yhB.y),
               (_Float16)(y6 - (float)yhB.z), (_Float16)(y7 - (float)yhB.w)};
    *(v4h*)&xs_hi[nl * 68 + (qq << 3) + 0] = yhA;
    *(v4h*)&xs_hi[nl * 68 + (qq << 3) + 4] = yhB;
    *(v4h*)&xs_lo[nl * 68 + (qq << 3) + 0] = ylA;
    *(v4h*)&xs_lo[nl * 68 + (qq << 3) + 4] = ylB;
    __syncthreads();

    // two row-tiles per wave: rows 0-15 and 16-31
    v4f acc0 = {0.f, 0.f, 0.f, 0.f};
    v4f acc1 = {0.f, 0.f, 0.f, 0.f};
    int ar = lane & 15;              // A: row = ar (+16), k = 16s + 4g + 0..3
#pragma unroll
    for (int s = 0; s < 4; s++) {
        int ko = (s << 4) + (g << 2);
        v4h al0 = *(const v4h*)&xs_lo[ar * 68 + ko];
        v4h ah0 = *(const v4h*)&xs_hi[ar * 68 + ko];
        v4h al1 = *(const v4h*)&xs_lo[(ar + 16) * 68 + ko];
        v4h ah1 = *(const v4h*)&xs_hi[(ar + 16) * 68 + ko];
        acc0 = __builtin_amdgcn_mfma_f32_16x16x16f16(al0, bf[s], acc0, 0, 0, 0);
        acc0 = __builtin_amdgcn_mfma_f32_16x16x16f16(ah0, bf[s], acc0, 0, 0, 0);
        acc1 = __builtin_amdgcn_mfma_f32_16x16x16f16(al1, bf[s], acc1, 0, 0, 0);
        acc1 = __builtin_amdgcn_mfma_f32_16x16x16f16(ah1, bf[s], acc1, 0, 0, 0);
    }

    // D: col = lane&15 (-> global col), row = 4g + j (+16 for tile 1). Scale
    // by the OUTPUT row's dinv (LDS, written pre-barrier), store fp16.
#pragma unroll
    for (int j = 0; j < 4; j++) {
        int r0 = (g << 2) + j;
        float v0 = acc0[j] * dsv[r0];
        outh[((size_t)(blockIdx.x * 32 + r0) << 6) + col] = __float2half(v0);
        int r1 = r0 + 16;
        float v1 = acc1[j] * dsv[r1];
        outh[((size_t)(blockIdx.x * 32 + r1) << 6) + col] = __float2half(v1);
    }
}

// Final gather, 32 nodes/block: out = relu(dinv_i*(gather h'_2) + b2), fp32.
__global__ __launch_bounds__(256) void k_gather(const uint4* __restrict__ h4,
                                                const int* __restrict__ csr,
                                                const int* __restrict__ deg,
                                                const float* __restrict__ bias,
                                                float* __restrict__ out, int n) {
    int t = threadIdx.x;
    int nl = t >> 3, qq = t & 7;
    int node = blockIdx.x * 32 + nl;
    if (node >= n) return;
    const int4* c4 = (const int4*)(csr + (node << 6));
    int4 ia0 = c4[0];                // idx hoist (see gather_acc4)
    int4 ib0 = c4[1];
    int dg = deg[node];
    int cnt = min(dg, CAP);
    float d = rsqrtf((float)(dg + 1));
    v4f aA, aB;
    gather_acc4(h4, csr, ia0, ib0, node, qq, cnt, aA, aB);
    float4 bA = ((const float4*)bias)[qq * 2 + 0];
    float4 bB = ((const float4*)bias)[qq * 2 + 1];
    float4 rA, rB;
    rA.x = fmaxf(fmaf(aA.x, d, bA.x), 0.f);
    rA.y = fmaxf(fmaf(aA.y, d, bA.y), 0.f);
    rA.z = fmaxf(fmaf(aA.z, d, bA.z), 0.f);
    rA.w = fmaxf(fmaf(aA.w, d, bA.w), 0.f);
    rB.x = fmaxf(fmaf(aB.x, d, bB.x), 0.f);
    rB.y = fmaxf(fmaf(aB.y, d, bB.y), 0.f);
    rB.z = fmaxf(fmaf(aB.z, d, bB.z), 0.f);
    rB.w = fmaxf(fmaf(aB.w, d, bB.w), 0.f);
    ((float4*)out)[(size_t)node * 16 + qq * 2 + 0] = rA;
    ((float4*)out)[(size_t)node * 16 + qq * 2 + 1] = rB;
}

// ---------------- launch ----------------

extern "C" void kernel_launch(void* const* d_in, const int* in_sizes, int n_in,
                              void* d_out, int out_size, void* d_ws, size_t ws_size,
                              hipStream_t stream) {
    const float* x  = (const float*)d_in[0];
    const int*   ei = (const int*)d_in[1];
    const float* W0 = (const float*)d_in[2];
    const float* b0 = (const float*)d_in[3];
    const float* W1 = (const float*)d_in[4];
    const float* b1 = (const float*)d_in[5];
    const float* W2 = (const float*)d_in[6];
    const float* b2 = (const float*)d_in[7];
    float* out = (float*)d_out;

    const int N = N_NODES;
    int E = in_sizes[1] / 2;
    const int* src = ei;
    const int* dst = ei + E;

    char* p = (char*)d_ws;
    auto alloc = [&](size_t bytes) -> void* {
        void* r = (void*)p;
        p += (bytes + 511) & ~(size_t)511;
        return r;
    };
    int*    deg  = (int*)alloc((size_t)N * 4);
    int*    rank = (int*)alloc((size_t)E * 4 + 1024);
    int*    csr  = (int*)alloc((size_t)N * CAP * 4);     // 25.6 MB fixed slots
    uint4*  hA   = (uint4*)alloc((size_t)N * 64 * 2);    // fp16 h', 12.8 MB
    uint4*  hB   = (uint4*)alloc((size_t)N * 64 * 2);
    __half* Wt0h = (__half*)alloc(4096 * 2);             // fp16 W^T, MFMA B operands
    __half* Wt0l = (__half*)alloc(4096 * 2);             // (W0 split hi+lo)
    __half* Wt1  = (__half*)alloc(4096 * 2);
    __half* Wt2  = (__half*)alloc(4096 * 2);

    const int GEMM_B = N / 16;               // 6250 (phaseB gemm half)
    const int GATH_B = N / 32;               // 3125 (32 nodes/block)
    const int EB = (E / 4 + 255) / 256 + 1;  // count/fill blocks (+1 remainder lane)

    (void)hipMemsetAsync(deg, 0, (size_t)N * 4, stream);
    // count alone with coalesced rank stores (atomic pipe tolerates nothing
    // co-resident); +1 block preps Wt tables
    k_count<<<EB + 1, 256, 0, stream>>>(dst, deg, rank, E,
                                        W0, W1, W2, Wt0h, Wt0l, Wt1, Wt2);
    // fill (scattered writes) || gemm0 (MFMA + read stream)
    k_phaseB<<<EB + GEMM_B, 256, 0, stream>>>(src, dst, rank, csr, E, EB,
                                              x, Wt0h, Wt0l, deg, (__half*)hA);
    // fused: gather(h'_0) -> y0 -> @W1 (MFMA) -> h'_1
    k_gather_gemm<<<GATH_B, 256, 0, stream>>>(hA, csr, deg, b0, Wt1, (__half*)hB, N);
    // fused: gather(h'_1) -> y1 -> @W2 (MFMA) -> h'_2
    k_gather_gemm<<<GATH_B, 256, 0, stream>>>(hB, csr, deg, b1, Wt2, (__half*)hA, N);
    // final gather -> out (fp32)
    k_gather<<<GATH_B, 256, 0, stream>>>(hA, csr, deg, b2, out, N);
}

// Round 6
// 232.727 us; speedup vs baseline: 1.1472x; 1.1082x over previous
//
#include <hip/hip_runtime.h>
#include <hip/hip_fp16.h>

#define N_NODES 100000
#define CAP 64    // fixed CSR slots per node; deg is Poisson(10), P(>64) ~ 1e-25
#define NB  391   // node buckets of 256 nodes: ceil(100000/256)
#define BE  2048  // edges per pass-1 block

typedef _Float16 v4h __attribute__((ext_vector_type(4)));
typedef float    v4f __attribute__((ext_vector_type(4)));

// ---------------- CSR build (atomic-free two-pass bucket build) ----------------
// Device-scope returning atomics are a ~17-20 G/s coherence-point wall (R1-R5:
// co-residency halves it, nt-hints no help, per-XCD replicas + workgroup scope
// change NOTHING). So: don't issue device atomics. LDS atomics are banked,
// per-CU, and fast.

// pass 1: per-block bucket sort of 2048 edges into 391 buckets (dst>>8).
// LDS histogram returns local rank; 3-step LDS exclusive scan gives bucket
// starts; edges land bucket-contiguous in the block's private arr slice as
// packed uint32 (dloc<<17 | src). scantab[blk][392] (uint16) = the scan row
// (entry 391 = block total). No global atomics, no overflow possible.
// Last grid block preps fp16 W^T tables instead (MFMA B operands); W0 gets a
// hi+lo split so layer 0 keeps near-fp32 precision.
__global__ __launch_bounds__(256) void k_bucket(
    const int* __restrict__ src, const int* __restrict__ dst, int E, int NBLK,
    unsigned int* __restrict__ arr, unsigned short* __restrict__ scantab,
    const float* __restrict__ W0, const float* __restrict__ W1,
    const float* __restrict__ W2,
    __half* __restrict__ Wt0h, __half* __restrict__ Wt0l,
    __half* __restrict__ Wt1, __half* __restrict__ Wt2) {
    if ((int)blockIdx.x == NBLK) {
        // Wt[c][k] = W[k][c]
        for (int i = threadIdx.x; i < 4096; i += 256) {
            int k = i >> 6, c = i & 63;
            float w0 = W0[i];
            __half w0h = __float2half(w0);
            Wt0h[(c << 6) + k] = w0h;
            Wt0l[(c << 6) + k] = __float2half(w0 - __half2float(w0h));
            Wt1[(c << 6) + k] = __float2half(W1[i]);
            Wt2[(c << 6) + k] = __float2half(W2[i]);
        }
        return;
    }
    __shared__ int cnt[392];   // 391 buckets + 1 pad (never hit) for the scan
    __shared__ int scn[392];
    __shared__ int gsum[98];
    int t = threadIdx.x;
    for (int j = t; j < 392; j += 256) cnt[j] = 0;
    __syncthreads();
    int blk = blockIdx.x;
    int base = blk * BE;
    int dsts[8], rnk[8];
#pragma unroll
    for (int i = 0; i < 8; i++) {          // coalesced: e = base + i*256 + t
        int e = base + i * 256 + t;
        int d = (e < E) ? dst[e] : -1;
        dsts[i] = d;
        rnk[i] = (d >= 0) ? atomicAdd(&cnt[d >> 8], 1) : 0;   // LDS atomic
    }
    __syncthreads();
    // exclusive scan of cnt[0..391] -> scn (3-step: 98 groups of 4)
    if (t < 98) gsum[t] = cnt[4 * t] + cnt[4 * t + 1] + cnt[4 * t + 2] + cnt[4 * t + 3];
    __syncthreads();
    if (t == 0) {
        int run = 0;
#pragma unroll 1
        for (int g = 0; g < 98; g++) { int c = gsum[g]; gsum[g] = run; run += c; }
    }
    __syncthreads();
    if (t < 98) {
        int b0 = gsum[t];
        int c0 = cnt[4 * t], c1 = cnt[4 * t + 1], c2 = cnt[4 * t + 2];
        scn[4 * t]     = b0;
        scn[4 * t + 1] = b0 + c0;
        scn[4 * t + 2] = b0 + c0 + c1;
        scn[4 * t + 3] = b0 + c0 + c1 + c2;
    }
    __syncthreads();
#pragma unroll
    for (int i = 0; i < 8; i++) {
        int d = dsts[i];
        if (d >= 0) {
            int e = base + i * 256 + t;
            int s = src[e];                 // coalesced reload
            int pos = scn[d >> 8] + rnk[i];
            arr[(size_t)blk * BE + pos] =
                ((unsigned)(d & 255) << 17) | (unsigned)s;   // src < 2^17
        }
    }
    for (int j = t; j < 392; j += 256)
        scantab[(size_t)blk * 392 + j] = (unsigned short)scn[j];
}

// pass 2: one block per bucket. Walks its scantab column, LDS-atomic ranks
// over 256 node counters (exclusive ownership -> correct), writes csr
// (exclusive 64 KB window) and deg (coalesced; replaces the memset — every
// node gets written, zero-deg included).
__global__ __launch_bounds__(256) void k_build(
    const unsigned int* __restrict__ arr,
    const unsigned short* __restrict__ scantab,
    int* __restrict__ csr, int* __restrict__ deg, int NBLK, int n) {
    __shared__ int cnt[256];
    int t = threadIdx.x;
    cnt[t] = 0;
    __syncthreads();
    int b = blockIdx.x;
    int bn = b << 8;
    for (int blk = t; blk < NBLK; blk += 256) {
        int s0 = scantab[(size_t)blk * 392 + b];
        int s1 = scantab[(size_t)blk * 392 + b + 1];
        const unsigned int* a = arr + (size_t)blk * BE;
        for (int k = s0; k < s1; k++) {
            unsigned v = a[k];
            int dloc = (int)(v >> 17);
            int sv = (int)(v & 0x1FFFF);
            int r = atomicAdd(&cnt[dloc], 1);          // LDS atomic
            if (r < CAP) csr[((bn + dloc) << 6) + r] = sv;
        }
    }
    __syncthreads();
    int nd = bn + t;
    if (nd < n) deg[nd] = cnt[t];
}

// gemm0 (solo now — fill no longer exists): h'0 = (x@W0)*dinv.
// MFMA: A = x hi/lo split, B = W0 hi/lo split -> near-fp32 product
// (xh*Wh + xl*Wh + xh*Wl; xl*Wl ~ 2^-22 rel).
__global__ __launch_bounds__(256) void k_gemm0(const float* __restrict__ x,
                                               const __half* __restrict__ Wth,
                                               const __half* __restrict__ Wtl,
                                               const int* __restrict__ deg,
                                               __half* __restrict__ outh) {
    __shared__ _Float16 xs_hi[16 * 68];   // stride 68: even bank spread for b64
    __shared__ _Float16 xs_lo[16 * 68];
    __shared__ float dsv[16];
    int t = threadIdx.x;
    int rl = t >> 4, q = t & 15;
    int lane = t & 63;
    int w = t >> 6;
    int col = (w << 4) + (lane & 15);
    int g = lane >> 4;
    int node = blockIdx.x * 16 + rl;

    v4f xv = __builtin_nontemporal_load((const v4f*)x + (size_t)blockIdx.x * 256 + t);
    int dg = deg[node];
    float d_i = rsqrtf((float)(dg + 1));
    if (q == 0) dsv[rl] = d_i;

    const v4h* wth4 = (const v4h*)(Wth + ((size_t)col << 6));
    const v4h* wtl4 = (const v4h*)(Wtl + ((size_t)col << 6));
    v4h bfh[4], bfl[4];
#pragma unroll
    for (int s = 0; s < 4; s++) { bfh[s] = wth4[(s << 2) + g]; bfl[s] = wtl4[(s << 2) + g]; }

    v4h yh = {(_Float16)xv.x, (_Float16)xv.y, (_Float16)xv.z, (_Float16)xv.w};
    v4h yl = {(_Float16)(xv.x - (float)yh.x), (_Float16)(xv.y - (float)yh.y),
              (_Float16)(xv.z - (float)yh.z), (_Float16)(xv.w - (float)yh.w)};
    *(v4h*)&xs_hi[rl * 68 + (q << 2)] = yh;
    *(v4h*)&xs_lo[rl * 68 + (q << 2)] = yl;
    __syncthreads();

    v4f acc = {0.f, 0.f, 0.f, 0.f};
    int arow = lane & 15;
#pragma unroll
    for (int s = 0; s < 4; s++) {
        v4h al = *(const v4h*)&xs_lo[arow * 68 + (s << 4) + (g << 2)];
        v4h ah = *(const v4h*)&xs_hi[arow * 68 + (s << 4) + (g << 2)];
        acc = __builtin_amdgcn_mfma_f32_16x16x16f16(al, bfh[s], acc, 0, 0, 0);
        acc = __builtin_amdgcn_mfma_f32_16x16x16f16(ah, bfl[s], acc, 0, 0, 0);
        acc = __builtin_amdgcn_mfma_f32_16x16x16f16(ah, bfh[s], acc, 0, 0, 0);
    }
#pragma unroll
    for (int j = 0; j < 4; j++) {
        int r = (g << 2) + j;
        float v = acc[j] * dsv[r];
        outh[((size_t)(blockIdx.x * 16 + r) << 6) + col] = __float2half(v);
    }
}

// ---------------- gather helpers (16B-granular) ----------------

// fp16 pairwise add of two gathered uint4s (8 halves): 4x v_pk_add_f16.
// Exactly ONE fp16 rounding per element (passed at 4.88e-4 total).
__device__ __forceinline__ uint4 padd4(uint4 u, uint4 v) {
    __half2* a = (__half2*)&u;
    __half2* b = (__half2*)&v;
    uint4 r;
    __half2* c = (__half2*)&r;
#pragma unroll
    for (int k = 0; k < 4; k++) c[k] = __hadd2(a[k], b[k]);
    return r;
}

// fp32 accumulate of 8 halves into two v4f
__device__ __forceinline__ void acc_h4(v4f& A, v4f& B, uint4 v) {
    __half2* h = (__half2*)&v;
    float2 f0 = __half22float2(h[0]);
    float2 f1 = __half22float2(h[1]);
    float2 f2 = __half22float2(h[2]);
    float2 f3 = __half22float2(h[3]);
    v4f fa = {f0.x, f0.y, f1.x, f1.y};
    v4f fb = {f2.x, f2.y, f3.x, f3.y};
    A = A + fa;
    B = B + fb;
}

// yA/yB = 8 columns of h'[node] + sum_j h'[j]; fp32 master acc, one fp16
// pairing level. 16B loads (uint4, 8 lanes/node). Caller pre-loads ia=c4[0],
// ib=c4[1] BEFORE the deg load so the deg->idx->gather chain collapses to one
// hop. Prefetched idx entries may read up to 28 B past the node's row
// (in-allocation) and are only USED when the count checks validate them.
__device__ __forceinline__ void gather_acc4(const uint4* __restrict__ h4,
                                            const int* __restrict__ csr,
                                            int4 ia, int4 ib,
                                            int node, int qq, int cnt,
                                            v4f& yA, v4f& yB) {
    const int4* c4 = (const int4*)(csr + (node << 6));
    v4f A0 = {0,0,0,0}, A1 = {0,0,0,0}, A2 = {0,0,0,0}, A3 = {0,0,0,0};
    v4f B0 = {0,0,0,0}, B1 = {0,0,0,0}, B2 = {0,0,0,0}, B3 = {0,0,0,0};
    acc_h4(A0, B0, h4[(size_t)node * 8 + qq]);  // self loop (fp32 path)
    int e = 0;
    for (; e + 8 <= cnt; ) {
        uint4 v0 = h4[(size_t)ia.x * 8 + qq];
        uint4 v1 = h4[(size_t)ia.y * 8 + qq];
        uint4 v2 = h4[(size_t)ia.z * 8 + qq];
        uint4 v3 = h4[(size_t)ia.w * 8 + qq];
        uint4 v4 = h4[(size_t)ib.x * 8 + qq];
        uint4 v5 = h4[(size_t)ib.y * 8 + qq];
        uint4 v6 = h4[(size_t)ib.z * 8 + qq];
        uint4 v7 = h4[(size_t)ib.w * 8 + qq];
        e += 8;
        ia = c4[e >> 2];            // prefetch overlaps the accumulate VALU below
        ib = c4[(e >> 2) + 1];
        uint4 p0 = padd4(v0, v1);
        uint4 p1 = padd4(v2, v3);
        uint4 p2 = padd4(v4, v5);
        uint4 p3 = padd4(v6, v7);
        acc_h4(A0, B0, p0); acc_h4(A1, B1, p1);
        acc_h4(A2, B2, p2); acc_h4(A3, B3, p3);
    }
    if (e + 4 <= cnt) {
        uint4 v0 = h4[(size_t)ia.x * 8 + qq];
        uint4 v1 = h4[(size_t)ia.y * 8 + qq];
        uint4 v2 = h4[(size_t)ia.z * 8 + qq];
        uint4 v3 = h4[(size_t)ia.w * 8 + qq];
        uint4 p0 = padd4(v0, v1);
        uint4 p1 = padd4(v2, v3);
        acc_h4(A1, B1, p0); acc_h4(A2, B2, p1);
        e += 4;
        ia = ib;                    // keep invariant ia = c4[e/4]
    }
    int rem = cnt - e;              // 0..3, one masked parallel iteration (fp32)
    if (rem > 0) {
        int j0 = ia.x;              // slot e < cnt -> valid
        int j1 = (rem > 1) ? ia.y : j0;
        int j2 = (rem > 2) ? ia.z : j0;
        uint4 v0 = h4[(size_t)j0 * 8 + qq];
        uint4 v1 = h4[(size_t)j1 * 8 + qq];
        uint4 v2 = h4[(size_t)j2 * 8 + qq];
        acc_h4(A1, B1, v0);
        if (rem > 1) acc_h4(A2, B2, v1);
        if (rem > 2) acc_h4(A3, B3, v2);
    }
    yA = (A0 + A1) + (A2 + A3);
    yB = (B0 + B1) + (B2 + B3);
}

// Fused interior layer, 32 nodes/block (8 lanes x 16B per node):
// y = relu(dinv_i*(gather h'_l) + b_l) -> h'_{l+1} = (y @ W_{l+1})*dinv_i.
// GEMM on MFMA: A = y split hi/lo fp16, B = Wt fp16 from global (L2-hot).
// Per wave: two 16x16 out tiles (rows 0-15 / 16-31), 16 MFMAs.
__global__ __launch_bounds__(256) void k_gather_gemm(const uint4* __restrict__ h4,
                                                     const int* __restrict__ csr,
                                                     const int* __restrict__ deg,
                                                     const float* __restrict__ bias,
                                                     const __half* __restrict__ Wt,
                                                     __half* __restrict__ outh, int n) {
    // row stride 68 halves (34 dwords ≡ 2 mod 32): b64 reads spread all banks
    __shared__ _Float16 xs_hi[32 * 68];
    __shared__ _Float16 xs_lo[32 * 68];
    __shared__ float dsv[32];
    (void)n;
    int t = threadIdx.x;
    int nl = t >> 3, qq = t & 7;     // 32 nodes/block, 8 lanes/node
    int node = blockIdx.x * 32 + nl;
    int lane = t & 63;
    int w = t >> 6;                  // wave id 0..3 -> out-col tile
    int col = (w << 4) + (lane & 15);
    int g = lane >> 4;               // k-subgroup within fragment

    const int4* c4 = (const int4*)(csr + (node << 6));
    int4 ia0 = c4[0];                // idx hoist: overlaps the deg load
    int4 ib0 = c4[1];
    int dg = deg[node];
    int cnt = min(dg, CAP);
    float d_i = rsqrtf((float)(dg + 1));
    if (qq == 0) dsv[nl] = d_i;
    float4 bA = ((const float4*)bias)[qq * 2 + 0];
    float4 bB = ((const float4*)bias)[qq * 2 + 1];

    v4f aA, aB;
    gather_acc4(h4, csr, ia0, ib0, node, qq, cnt, aA, aB);

    // B fragments (lane: B[k][j], j -> col, k=16s+4g..+3): issue now, latency
    // hides under relu/convert/LDS-write/barrier.
    const v4h* wt4 = (const v4h*)(Wt + ((size_t)col << 6));
    v4h bf[4];
#pragma unroll
    for (int s = 0; s < 4; s++) bf[s] = wt4[(s << 2) + g];

    float y0 = fmaxf(fmaf(aA.x, d_i, bA.x), 0.f);
    float y1 = fmaxf(fmaf(aA.y, d_i, bA.y), 0.f);
    float y2 = fmaxf(fmaf(aA.z, d_i, bA.z), 0.f);
    float y3 = fmaxf(fmaf(aA.w, d_i, bA.w), 0.f);
    float y4 = fmaxf(fmaf(aB.x, d_i, bB.x), 0.f);
    float y5 = fmaxf(fmaf(aB.y, d_i, bB.y), 0.f);
    float y6 = fmaxf(fmaf(aB.z, d_i, bB.z), 0.f);
    float y7 = fmaxf(fmaf(aB.w, d_i, bB.w), 0.f);
    v4h yhA = {(_Float16)y0, (_Float16)y1, (_Float16)y2, (_Float16)y3};
    v4h ylA = {(_Float16)(y0 - (float)yhA.x), (_Float16)(y1 - (float)yhA.y),
               (_Float16)(y2 - (float)yhA.z), (_Float16)(y3 - (float)yhA.w)};
    v4h yhB = {(_Float16)y4, (_Float16)y5, (_Float16)y6, (_Float16)y7};
    v4h ylB = {(_Float16)(y4 - (float)yhB.x), (_Float16)(y5 - (float)yhB.y),
               (_Float16)(y6 - (float)yhB.z), (_Float16)(y7 - (float)yhB.w)};
    *(v4h*)&xs_hi[nl * 68 + (qq << 3) + 0] = yhA;
    *(v4h*)&xs_hi[nl * 68 + (qq << 3) + 4] = yhB;
    *(v4h*)&xs_lo[nl * 68 + (qq << 3) + 0] = ylA;
    *(v4h*)&xs_lo[nl * 68 + (qq << 3) + 4] = ylB;
    __syncthreads();

    // two row-tiles per wave: rows 0-15 and 16-31
    v4f acc0 = {0.f, 0.f, 0.f, 0.f};
    v4f acc1 = {0.f, 0.f, 0.f, 0.f};
    int ar = lane & 15;              // A: row = ar (+16), k = 16s + 4g + 0..3
#pragma unroll
    for (int s = 0; s < 4; s++) {
        int ko = (s << 4) + (g << 2);
        v4h al0 = *(const v4h*)&xs_lo[ar * 68 + ko];
        v4h ah0 = *(const v4h*)&xs_hi[ar * 68 + ko];
        v4h al1 = *(const v4h*)&xs_lo[(ar + 16) * 68 + ko];
        v4h ah1 = *(const v4h*)&xs_hi[(ar + 16) * 68 + ko];
        acc0 = __builtin_amdgcn_mfma_f32_16x16x16f16(al0, bf[s], acc0, 0, 0, 0);
        acc0 = __builtin_amdgcn_mfma_f32_16x16x16f16(ah0, bf[s], acc0, 0, 0, 0);
        acc1 = __builtin_amdgcn_mfma_f32_16x16x16f16(al1, bf[s], acc1, 0, 0, 0);
        acc1 = __builtin_amdgcn_mfma_f32_16x16x16f16(ah1, bf[s], acc1, 0, 0, 0);
    }

    // D: col = lane&15 (-> global col), row = 4g + j (+16 for tile 1). Scale
    // by the OUTPUT row's dinv (LDS, written pre-barrier), store fp16.
#pragma unroll
    for (int j = 0; j < 4; j++) {
        int r0 = (g << 2) + j;
        float v0 = acc0[j] * dsv[r0];
        outh[((size_t)(blockIdx.x * 32 + r0) << 6) + col] = __float2half(v0);
        int r1 = r0 + 16;
        float v1 = acc1[j] * dsv[r1];
        outh[((size_t)(blockIdx.x * 32 + r1) << 6) + col] = __float2half(v1);
    }
}

// Final gather, 32 nodes/block: out = relu(dinv_i*(gather h'_2) + b2), fp32.
__global__ __launch_bounds__(256) void k_gather(const uint4* __restrict__ h4,
                                                const int* __restrict__ csr,
                                                const int* __restrict__ deg,
                                                const float* __restrict__ bias,
                                                float* __restrict__ out, int n) {
    int t = threadIdx.x;
    int nl = t >> 3, qq = t & 7;
    int node = blockIdx.x * 32 + nl;
    if (node >= n) return;
    const int4* c4 = (const int4*)(csr + (node << 6));
    int4 ia0 = c4[0];                // idx hoist (see gather_acc4)
    int4 ib0 = c4[1];
    int dg = deg[node];
    int cnt = min(dg, CAP);
    float d = rsqrtf((float)(dg + 1));
    v4f aA, aB;
    gather_acc4(h4, csr, ia0, ib0, node, qq, cnt, aA, aB);
    float4 bA = ((const float4*)bias)[qq * 2 + 0];
    float4 bB = ((const float4*)bias)[qq * 2 + 1];
    float4 rA, rB;
    rA.x = fmaxf(fmaf(aA.x, d, bA.x), 0.f);
    rA.y = fmaxf(fmaf(aA.y, d, bA.y), 0.f);
    rA.z = fmaxf(fmaf(aA.z, d, bA.z), 0.f);
    rA.w = fmaxf(fmaf(aA.w, d, bA.w), 0.f);
    rB.x = fmaxf(fmaf(aB.x, d, bB.x), 0.f);
    rB.y = fmaxf(fmaf(aB.y, d, bB.y), 0.f);
    rB.z = fmaxf(fmaf(aB.z, d, bB.z), 0.f);
    rB.w = fmaxf(fmaf(aB.w, d, bB.w), 0.f);
    ((float4*)out)[(size_t)node * 16 + qq * 2 + 0] = rA;
    ((float4*)out)[(size_t)node * 16 + qq * 2 + 1] = rB;
}

// ---------------- launch ----------------

extern "C" void kernel_launch(void* const* d_in, const int* in_sizes, int n_in,
                              void* d_out, int out_size, void* d_ws, size_t ws_size,
                              hipStream_t stream) {
    const float* x  = (const float*)d_in[0];
    const int*   ei = (const int*)d_in[1];
    const float* W0 = (const float*)d_in[2];
    const float* b0 = (const float*)d_in[3];
    const float* W1 = (const float*)d_in[4];
    const float* b1 = (const float*)d_in[5];
    const float* W2 = (const float*)d_in[6];
    const float* b2 = (const float*)d_in[7];
    float* out = (float*)d_out;

    const int N = N_NODES;
    int E = in_sizes[1] / 2;
    const int* src = ei;
    const int* dst = ei + E;
    const int NBLK = (E + BE - 1) / BE;      // pass-1 blocks

    char* p = (char*)d_ws;
    auto alloc = [&](size_t bytes) -> void* {
        void* r = (void*)p;
        p += (bytes + 511) & ~(size_t)511;
        return r;
    };
    int*    deg  = (int*)alloc((size_t)N * 4);
    unsigned int*   arr     = (unsigned int*)alloc((size_t)NBLK * BE * 4);   // ~4 MB
    unsigned short* scantab = (unsigned short*)alloc((size_t)NBLK * 392 * 2);// ~0.4 MB
    int*    csr  = (int*)alloc((size_t)N * CAP * 4);     // 25.6 MB fixed slots
    uint4*  hA   = (uint4*)alloc((size_t)N * 64 * 2);    // fp16 h', 12.8 MB
    uint4*  hB   = (uint4*)alloc((size_t)N * 64 * 2);
    __half* Wt0h = (__half*)alloc(4096 * 2);             // fp16 W^T, MFMA B operands
    __half* Wt0l = (__half*)alloc(4096 * 2);             // (W0 split hi+lo)
    __half* Wt1  = (__half*)alloc(4096 * 2);
    __half* Wt2  = (__half*)alloc(4096 * 2);

    const int GEMM_B = N / 16;               // 6250
    const int GATH_B = N / 32;               // 3125 (32 nodes/block)

    // pass 1: bucket-sort edges (LDS atomics only); +1 block preps Wt tables
    k_bucket<<<NBLK + 1, 256, 0, stream>>>(src, dst, E, NBLK, arr, scantab,
                                           W0, W1, W2, Wt0h, Wt0l, Wt1, Wt2);
    // pass 2: per-bucket rank + csr fill + deg write (replaces memset too)
    k_build<<<NB, 256, 0, stream>>>(arr, scantab, csr, deg, NBLK, N);
    // h'0 = (x@W0)*dinv, MFMA hi/lo x hi/lo (solo — nothing left to co-run)
    k_gemm0<<<GEMM_B, 256, 0, stream>>>(x, Wt0h, Wt0l, deg, (__half*)hA);
    // fused: gather(h'_0) -> y0 -> @W1 (MFMA) -> h'_1
    k_gather_gemm<<<GATH_B, 256, 0, stream>>>(hA, csr, deg, b0, Wt1, (__half*)hB, N);
    // fused: gather(h'_1) -> y1 -> @W2 (MFMA) -> h'_2
    k_gather_gemm<<<GATH_B, 256, 0, stream>>>(hB, csr, deg, b1, Wt2, (__half*)hA, N);
    // final gather -> out (fp32)
    k_gather<<<GATH_B, 256, 0, stream>>>(hA, csr, deg, b2, out, N);
}

// Round 7
// 219.395 us; speedup vs baseline: 1.2169x; 1.0608x over previous
//
#include <hip/hip_runtime.h>
#include <hip/hip_fp16.h>

#define N_NODES 100000
#define CAP 64    // fixed CSR slots per node; deg is Poisson(10), P(>64) ~ 1e-25
#define NB  391   // node buckets of 256 nodes: ceil(100000/256)
#define BE  2048  // edges per pass-1 block

typedef _Float16 v4h __attribute__((ext_vector_type(4)));
typedef float    v4f __attribute__((ext_vector_type(4)));

// ---------------- CSR build (atomic-free two-pass bucket build) ----------------
// Device-scope returning atomics are a ~17-20 G/s coherence-point wall (R1-R5:
// co-residency halves it, nt-hints no help, per-XCD replicas + workgroup scope
// change NOTHING). So: no device atomics anywhere. LDS atomics are banked,
// per-CU, and fast.

// pass 1: per-block bucket sort of 2048 edges into 391 buckets (dst>>8).
// LDS histogram returns local rank; parallel (Hillis-Steele) exclusive scan
// gives bucket starts; edges land bucket-contiguous in the block's private arr
// slice as packed uint32 (dloc<<17 | src). scantab[blk][392] (uint16) = scan
// row (entry 391 = block total). No overflow possible.
// Last grid block preps fp16 W^T tables instead (MFMA B operands); W0 gets a
// hi+lo split so layer 0 keeps near-fp32 precision.
__global__ __launch_bounds__(256) void k_bucket(
    const int* __restrict__ src, const int* __restrict__ dst, int E, int NBLK,
    unsigned int* __restrict__ arr, unsigned short* __restrict__ scantab,
    const float* __restrict__ W0, const float* __restrict__ W1,
    const float* __restrict__ W2,
    __half* __restrict__ Wt0h, __half* __restrict__ Wt0l,
    __half* __restrict__ Wt1, __half* __restrict__ Wt2) {
    if ((int)blockIdx.x == NBLK) {
        // Wt[c][k] = W[k][c]
        for (int i = threadIdx.x; i < 4096; i += 256) {
            int k = i >> 6, c = i & 63;
            float w0 = W0[i];
            __half w0h = __float2half(w0);
            Wt0h[(c << 6) + k] = w0h;
            Wt0l[(c << 6) + k] = __float2half(w0 - __half2float(w0h));
            Wt1[(c << 6) + k] = __float2half(W1[i]);
            Wt2[(c << 6) + k] = __float2half(W2[i]);
        }
        return;
    }
    __shared__ int cnt[392];   // 391 buckets + 1 pad (never hit) for the scan
    __shared__ int scn[392];
    __shared__ int gs[98];     // 98 groups of 4 for the scan
    int t = threadIdx.x;
    for (int j = t; j < 392; j += 256) cnt[j] = 0;
    __syncthreads();
    int blk = blockIdx.x;
    int base = blk * BE;
    int dsts[8], srcs[8], rnk[8];
#pragma unroll
    for (int i = 0; i < 8; i++) {          // coalesced: e = base + i*256 + t
        int e = base + i * 256 + t;
        int d = (e < E) ? dst[e] : -1;
        srcs[i] = (e < E) ? src[e] : 0;
        dsts[i] = d;
        rnk[i] = (d >= 0) ? atomicAdd(&cnt[d >> 8], 1) : 0;   // LDS atomic
    }
    __syncthreads();
    // exclusive scan of cnt[0..391] -> scn: group sums, Hillis-Steele over 98
    int c0 = 0, c1 = 0, c2 = 0, c3 = 0;
    if (t < 98) {
        c0 = cnt[4 * t]; c1 = cnt[4 * t + 1]; c2 = cnt[4 * t + 2]; c3 = cnt[4 * t + 3];
        gs[t] = c0 + c1 + c2 + c3;
    }
    __syncthreads();
#pragma unroll
    for (int off = 1; off < 128; off <<= 1) {
        int u = (t < 98 && t >= off) ? gs[t - off] : 0;
        __syncthreads();
        if (t < 98) gs[t] += u;
        __syncthreads();
    }
    if (t < 98) {
        int b0 = gs[t] - (c0 + c1 + c2 + c3);   // exclusive group base
        scn[4 * t]     = b0;
        scn[4 * t + 1] = b0 + c0;
        scn[4 * t + 2] = b0 + c0 + c1;
        scn[4 * t + 3] = b0 + c0 + c1 + c2;
    }
    __syncthreads();
#pragma unroll
    for (int i = 0; i < 8; i++) {
        int d = dsts[i];
        if (d >= 0) {
            int pos = scn[d >> 8] + rnk[i];
            arr[(size_t)blk * BE + pos] =
                ((unsigned)(d & 255) << 17) | (unsigned)srcs[i];   // src < 2^17
        }
    }
    for (int j = t; j < 392; j += 256)
        scantab[(size_t)blk * 392 + j] = (unsigned short)scn[j];
}

// pass 2 FUSED with gemm0: one block per bucket (256 nodes).
// Phase A: walk the scantab column, LDS-atomic rank over 256 node counters,
//          scatter edges into the bucket's CSR window staged in LDS (64 KB) —
//          LDS eats the scatter, global sees nothing.
// Phase B: stream the window out as coalesced int4 (25.6 MB sequential
//          device-wide vs 1M random dwords before) + write deg.
// Phase C: gemm0 for the SAME 256 nodes — h'0 = (x@W0)*dinv — reading the
//          node counts straight from LDS cnt (no deg round-trip, no extra
//          launch). A = x hi/lo split, B = W0 hi/lo split -> near-fp32
//          product (xh*Wh + xl*Wh + xh*Wl; xl*Wl ~ 2^-22 rel).
__global__ __launch_bounds__(256) void k_build0(
    const unsigned int* __restrict__ arr,
    const unsigned short* __restrict__ scantab,
    int* __restrict__ csr, int* __restrict__ deg, int NBLK, int n,
    const float* __restrict__ x,
    const __half* __restrict__ Wth, const __half* __restrict__ Wtl,
    __half* __restrict__ outh) {
    __shared__ int4 lcsr4[4096];          // 64 KB: 256 nodes x 64 slots
    __shared__ int cnt[256];
    __shared__ _Float16 xs_hi[16 * 68];   // stride 68: even bank spread for b64
    __shared__ _Float16 xs_lo[16 * 68];
    int* lcsr = (int*)lcsr4;
    int t = threadIdx.x;
    cnt[t] = 0;
    __syncthreads();
    int b = blockIdx.x;
    int bn = b << 8;
    // ---- phase A: rank + LDS scatter ----
    for (int blk = t; blk < NBLK; blk += 256) {
        int s0 = scantab[(size_t)blk * 392 + b];
        int s1 = scantab[(size_t)blk * 392 + b + 1];
        const unsigned int* a = arr + (size_t)blk * BE;
        for (int k = s0; k < s1; k++) {
            unsigned v = a[k];
            int dloc = (int)(v >> 17);
            int sv = (int)(v & 0x1FFFF);
            int r = atomicAdd(&cnt[dloc], 1);          // LDS atomic
            if (r < CAP) lcsr[(dloc << 6) + r] = sv;
        }
    }
    __syncthreads();
    // ---- phase B: coalesced writeout + deg ----
    int rows = min(256, n - bn);          // last bucket: 160 (multiple of 16)
    int4* cdst = (int4*)(csr + ((size_t)bn << 6));
    for (int i = t; i < rows * 16; i += 256) cdst[i] = lcsr4[i];
    if (bn + t < n) deg[bn + t] = cnt[t];
    // ---- phase C: gemm0 for these nodes, 16 tiles of 16 ----
    int rl = t >> 4, q = t & 15;
    int lane = t & 63;
    int w = t >> 6;
    int col = (w << 4) + (lane & 15);
    int g = lane >> 4;
    const v4h* wth4 = (const v4h*)(Wth + ((size_t)col << 6));
    const v4h* wtl4 = (const v4h*)(Wtl + ((size_t)col << 6));
    v4h bfh[4], bfl[4];
#pragma unroll
    for (int s = 0; s < 4; s++) { bfh[s] = wth4[(s << 2) + g]; bfl[s] = wtl4[(s << 2) + g]; }

    int tiles = rows >> 4;
    for (int it = 0; it < tiles; it++) {
        int nb16 = bn + it * 16;          // tile's first node
        v4f xv = __builtin_nontemporal_load((const v4f*)x + (size_t)nb16 * 16 + t);
        float d_i = rsqrtf((float)(cnt[it * 16 + rl] + 1));
        v4h yh = {(_Float16)xv.x, (_Float16)xv.y, (_Float16)xv.z, (_Float16)xv.w};
        v4h yl = {(_Float16)(xv.x - (float)yh.x), (_Float16)(xv.y - (float)yh.y),
                  (_Float16)(xv.z - (float)yh.z), (_Float16)(xv.w - (float)yh.w)};
        (void)d_i;  // dinv applied per OUTPUT row below (same value, row indexed)
        *(v4h*)&xs_hi[rl * 68 + (q << 2)] = yh;
        *(v4h*)&xs_lo[rl * 68 + (q << 2)] = yl;
        __syncthreads();
        v4f acc = {0.f, 0.f, 0.f, 0.f};
        int arow = lane & 15;
#pragma unroll
        for (int s = 0; s < 4; s++) {
            v4h al = *(const v4h*)&xs_lo[arow * 68 + (s << 4) + (g << 2)];
            v4h ah = *(const v4h*)&xs_hi[arow * 68 + (s << 4) + (g << 2)];
            acc = __builtin_amdgcn_mfma_f32_16x16x16f16(al, bfh[s], acc, 0, 0, 0);
            acc = __builtin_amdgcn_mfma_f32_16x16x16f16(ah, bfl[s], acc, 0, 0, 0);
            acc = __builtin_amdgcn_mfma_f32_16x16x16f16(ah, bfh[s], acc, 0, 0, 0);
        }
#pragma unroll
        for (int j = 0; j < 4; j++) {
            int r = (g << 2) + j;
            float dr = rsqrtf((float)(cnt[it * 16 + r] + 1));
            float v = acc[j] * dr;
            outh[((size_t)(nb16 + r) << 6) + col] = __float2half(v);
        }
        __syncthreads();                  // xs reused next tile
    }
}

// ---------------- gather helpers (16B-granular) ----------------

// fp16 pairwise add of two gathered uint4s (8 halves): 4x v_pk_add_f16.
// Exactly ONE fp16 rounding per element (passed at 4.88e-4 total).
__device__ __forceinline__ uint4 padd4(uint4 u, uint4 v) {
    __half2* a = (__half2*)&u;
    __half2* b = (__half2*)&v;
    uint4 r;
    __half2* c = (__half2*)&r;
#pragma unroll
    for (int k = 0; k < 4; k++) c[k] = __hadd2(a[k], b[k]);
    return r;
}

// fp32 accumulate of 8 halves into two v4f
__device__ __forceinline__ void acc_h4(v4f& A, v4f& B, uint4 v) {
    __half2* h = (__half2*)&v;
    float2 f0 = __half22float2(h[0]);
    float2 f1 = __half22float2(h[1]);
    float2 f2 = __half22float2(h[2]);
    float2 f3 = __half22float2(h[3]);
    v4f fa = {f0.x, f0.y, f1.x, f1.y};
    v4f fb = {f2.x, f2.y, f3.x, f3.y};
    A = A + fa;
    B = B + fb;
}

// yA/yB = 8 columns of h'[node] + sum_j h'[j]; fp32 master acc, one fp16
// pairing level. 16B loads (uint4, 8 lanes/node). Caller pre-loads ia=c4[0],
// ib=c4[1] BEFORE the deg load so the deg->idx->gather chain collapses to one
// hop. Prefetched idx entries may read up to 28 B past the node's row
// (in-allocation) and are only USED when the count checks validate them.
__device__ __forceinline__ void gather_acc4(const uint4* __restrict__ h4,
                                            const int* __restrict__ csr,
                                            int4 ia, int4 ib,
                                            int node, int qq, int cnt,
                                            v4f& yA, v4f& yB) {
    const int4* c4 = (const int4*)(csr + (node << 6));
    v4f A0 = {0,0,0,0}, A1 = {0,0,0,0}, A2 = {0,0,0,0}, A3 = {0,0,0,0};
    v4f B0 = {0,0,0,0}, B1 = {0,0,0,0}, B2 = {0,0,0,0}, B3 = {0,0,0,0};
    acc_h4(A0, B0, h4[(size_t)node * 8 + qq]);  // self loop (fp32 path)
    int e = 0;
    for (; e + 8 <= cnt; ) {
        uint4 v0 = h4[(size_t)ia.x * 8 + qq];
        uint4 v1 = h4[(size_t)ia.y * 8 + qq];
        uint4 v2 = h4[(size_t)ia.z * 8 + qq];
        uint4 v3 = h4[(size_t)ia.w * 8 + qq];
        uint4 v4 = h4[(size_t)ib.x * 8 + qq];
        uint4 v5 = h4[(size_t)ib.y * 8 + qq];
        uint4 v6 = h4[(size_t)ib.z * 8 + qq];
        uint4 v7 = h4[(size_t)ib.w * 8 + qq];
        e += 8;
        ia = c4[e >> 2];            // prefetch overlaps the accumulate VALU below
        ib = c4[(e >> 2) + 1];
        uint4 p0 = padd4(v0, v1);
        uint4 p1 = padd4(v2, v3);
        uint4 p2 = padd4(v4, v5);
        uint4 p3 = padd4(v6, v7);
        acc_h4(A0, B0, p0); acc_h4(A1, B1, p1);
        acc_h4(A2, B2, p2); acc_h4(A3, B3, p3);
    }
    if (e + 4 <= cnt) {
        uint4 v0 = h4[(size_t)ia.x * 8 + qq];
        uint4 v1 = h4[(size_t)ia.y * 8 + qq];
        uint4 v2 = h4[(size_t)ia.z * 8 + qq];
        uint4 v3 = h4[(size_t)ia.w * 8 + qq];
        uint4 p0 = padd4(v0, v1);
        uint4 p1 = padd4(v2, v3);
        acc_h4(A1, B1, p0); acc_h4(A2, B2, p1);
        e += 4;
        ia = ib;                    // keep invariant ia = c4[e/4]
    }
    int rem = cnt - e;              // 0..3, one masked parallel iteration (fp32)
    if (rem > 0) {
        int j0 = ia.x;              // slot e < cnt -> valid
        int j1 = (rem > 1) ? ia.y : j0;
        int j2 = (rem > 2) ? ia.z : j0;
        uint4 v0 = h4[(size_t)j0 * 8 + qq];
        uint4 v1 = h4[(size_t)j1 * 8 + qq];
        uint4 v2 = h4[(size_t)j2 * 8 + qq];
        acc_h4(A1, B1, v0);
        if (rem > 1) acc_h4(A2, B2, v1);
        if (rem > 2) acc_h4(A3, B3, v2);
    }
    yA = (A0 + A1) + (A2 + A3);
    yB = (B0 + B1) + (B2 + B3);
}

// Fused interior layer, 32 nodes/block (8 lanes x 16B per node):
// y = relu(dinv_i*(gather h'_l) + b_l) -> h'_{l+1} = (y @ W_{l+1})*dinv_i.
// GEMM on MFMA: A = y split hi/lo fp16, B = Wt fp16 from global (L2-hot).
// Per wave: two 16x16 out tiles (rows 0-15 / 16-31), 16 MFMAs.
__global__ __launch_bounds__(256) void k_gather_gemm(const uint4* __restrict__ h4,
                                                     const int* __restrict__ csr,
                                                     const int* __restrict__ deg,
                                                     const float* __restrict__ bias,
                                                     const __half* __restrict__ Wt,
                                                     __half* __restrict__ outh, int n) {
    // row stride 68 halves (34 dwords ≡ 2 mod 32): b64 reads spread all banks
    __shared__ _Float16 xs_hi[32 * 68];
    __shared__ _Float16 xs_lo[32 * 68];
    __shared__ float dsv[32];
    (void)n;
    int t = threadIdx.x;
    int nl = t >> 3, qq = t & 7;     // 32 nodes/block, 8 lanes/node
    int node = blockIdx.x * 32 + nl;
    int lane = t & 63;
    int w = t >> 6;                  // wave id 0..3 -> out-col tile
    int col = (w << 4) + (lane & 15);
    int g = lane >> 4;               // k-subgroup within fragment

    const int4* c4 = (const int4*)(csr + (node << 6));
    int4 ia0 = c4[0];                // idx hoist: overlaps the deg load
    int4 ib0 = c4[1];
    int dg = deg[node];
    int cnt = min(dg, CAP);
    float d_i = rsqrtf((float)(dg + 1));
    if (qq == 0) dsv[nl] = d_i;
    float4 bA = ((const float4*)bias)[qq * 2 + 0];
    float4 bB = ((const float4*)bias)[qq * 2 + 1];

    v4f aA, aB;
    gather_acc4(h4, csr, ia0, ib0, node, qq, cnt, aA, aB);

    // B fragments (lane: B[k][j], j -> col, k=16s+4g..+3): issue now, latency
    // hides under relu/convert/LDS-write/barrier.
    const v4h* wt4 = (const v4h*)(Wt + ((size_t)col << 6));
    v4h bf[4];
#pragma unroll
    for (int s = 0; s < 4; s++) bf[s] = wt4[(s << 2) + g];

    float y0 = fmaxf(fmaf(aA.x, d_i, bA.x), 0.f);
    float y1 = fmaxf(fmaf(aA.y, d_i, bA.y), 0.f);
    float y2 = fmaxf(fmaf(aA.z, d_i, bA.z), 0.f);
    float y3 = fmaxf(fmaf(aA.w, d_i, bA.w), 0.f);
    float y4 = fmaxf(fmaf(aB.x, d_i, bB.x), 0.f);
    float y5 = fmaxf(fmaf(aB.y, d_i, bB.y), 0.f);
    float y6 = fmaxf(fmaf(aB.z, d_i, bB.z), 0.f);
    float y7 = fmaxf(fmaf(aB.w, d_i, bB.w), 0.f);
    v4h yhA = {(_Float16)y0, (_Float16)y1, (_Float16)y2, (_Float16)y3};
    v4h ylA = {(_Float16)(y0 - (float)yhA.x), (_Float16)(y1 - (float)yhA.y),
               (_Float16)(y2 - (float)yhA.z), (_Float16)(y3 - (float)yhA.w)};
    v4h yhB = {(_Float16)y4, (_Float16)y5, (_Float16)y6, (_Float16)y7};
    v4h ylB = {(_Float16)(y4 - (float)yhB.x), (_Float16)(y5 - (float)yhB.y),
               (_Float16)(y6 - (float)yhB.z), (_Float16)(y7 - (float)yhB.w)};
    *(v4h*)&xs_hi[nl * 68 + (qq << 3) + 0] = yhA;
    *(v4h*)&xs_hi[nl * 68 + (qq << 3) + 4] = yhB;
    *(v4h*)&xs_lo[nl * 68 + (qq << 3) + 0] = ylA;
    *(v4h*)&xs_lo[nl * 68 + (qq << 3) + 4] = ylB;
    __syncthreads();

    // two row-tiles per wave: rows 0-15 and 16-31
    v4f acc0 = {0.f, 0.f, 0.f, 0.f};
    v4f acc1 = {0.f, 0.f, 0.f, 0.f};
    int ar = lane & 15;              // A: row = ar (+16), k = 16s + 4g + 0..3
#pragma unroll
    for (int s = 0; s < 4; s++) {
        int ko = (s << 4) + (g << 2);
        v4h al0 = *(const v4h*)&xs_lo[ar * 68 + ko];
        v4h ah0 = *(const v4h*)&xs_hi[ar * 68 + ko];
        v4h al1 = *(const v4h*)&xs_lo[(ar + 16) * 68 + ko];
        v4h ah1 = *(const v4h*)&xs_hi[(ar + 16) * 68 + ko];
        acc0 = __builtin_amdgcn_mfma_f32_16x16x16f16(al0, bf[s], acc0, 0, 0, 0);
        acc0 = __builtin_amdgcn_mfma_f32_16x16x16f16(ah0, bf[s], acc0, 0, 0, 0);
        acc1 = __builtin_amdgcn_mfma_f32_16x16x16f16(al1, bf[s], acc1, 0, 0, 0);
        acc1 = __builtin_amdgcn_mfma_f32_16x16x16f16(ah1, bf[s], acc1, 0, 0, 0);
    }

    // D: col = lane&15 (-> global col), row = 4g + j (+16 for tile 1). Scale
    // by the OUTPUT row's dinv (LDS, written pre-barrier), store fp16.
#pragma unroll
    for (int j = 0; j < 4; j++) {
        int r0 = (g << 2) + j;
        float v0 = acc0[j] * dsv[r0];
        outh[((size_t)(blockIdx.x * 32 + r0) << 6) + col] = __float2half(v0);
        int r1 = r0 + 16;
        float v1 = acc1[j] * dsv[r1];
        outh[((size_t)(blockIdx.x * 32 + r1) << 6) + col] = __float2half(v1);
    }
}

// Final gather, 32 nodes/block: out = relu(dinv_i*(gather h'_2) + b2), fp32.
__global__ __launch_bounds__(256) void k_gather(const uint4* __restrict__ h4,
                                                const int* __restrict__ csr,
                                                const int* __restrict__ deg,
                                                const float* __restrict__ bias,
                                                float* __restrict__ out, int n) {
    int t = threadIdx.x;
    int nl = t >> 3, qq = t & 7;
    int node = blockIdx.x * 32 + nl;
    if (node >= n) return;
    const int4* c4 = (const int4*)(csr + (node << 6));
    int4 ia0 = c4[0];                // idx hoist (see gather_acc4)
    int4 ib0 = c4[1];
    int dg = deg[node];
    int cnt = min(dg, CAP);
    float d = rsqrtf((float)(dg + 1));
    v4f aA, aB;
    gather_acc4(h4, csr, ia0, ib0, node, qq, cnt, aA, aB);
    float4 bA = ((const float4*)bias)[qq * 2 + 0];
    float4 bB = ((const float4*)bias)[qq * 2 + 1];
    float4 rA, rB;
    rA.x = fmaxf(fmaf(aA.x, d, bA.x), 0.f);
    rA.y = fmaxf(fmaf(aA.y, d, bA.y), 0.f);
    rA.z = fmaxf(fmaf(aA.z, d, bA.z), 0.f);
    rA.w = fmaxf(fmaf(aA.w, d, bA.w), 0.f);
    rB.x = fmaxf(fmaf(aB.x, d, bB.x), 0.f);
    rB.y = fmaxf(fmaf(aB.y, d, bB.y), 0.f);
    rB.z = fmaxf(fmaf(aB.z, d, bB.z), 0.f);
    rB.w = fmaxf(fmaf(aB.w, d, bB.w), 0.f);
    ((float4*)out)[(size_t)node * 16 + qq * 2 + 0] = rA;
    ((float4*)out)[(size_t)node * 16 + qq * 2 + 1] = rB;
}

// ---------------- launch ----------------

extern "C" void kernel_launch(void* const* d_in, const int* in_sizes, int n_in,
                              void* d_out, int out_size, void* d_ws, size_t ws_size,
                              hipStream_t stream) {
    const float* x  = (const float*)d_in[0];
    const int*   ei = (const int*)d_in[1];
    const float* W0 = (const float*)d_in[2];
    const float* b0 = (const float*)d_in[3];
    const float* W1 = (const float*)d_in[4];
    const float* b1 = (const float*)d_in[5];
    const float* W2 = (const float*)d_in[6];
    const float* b2 = (const float*)d_in[7];
    float* out = (float*)d_out;

    const int N = N_NODES;
    int E = in_sizes[1] / 2;
    const int* src = ei;
    const int* dst = ei + E;
    const int NBLK = (E + BE - 1) / BE;      // pass-1 blocks

    char* p = (char*)d_ws;
    auto alloc = [&](size_t bytes) -> void* {
        void* r = (void*)p;
        p += (bytes + 511) & ~(size_t)511;
        return r;
    };
    int*    deg  = (int*)alloc((size_t)N * 4);
    unsigned int*   arr     = (unsigned int*)alloc((size_t)NBLK * BE * 4);   // ~4 MB
    unsigned short* scantab = (unsigned short*)alloc((size_t)NBLK * 392 * 2);// ~0.4 MB
    int*    csr  = (int*)alloc((size_t)N * CAP * 4);     // 25.6 MB fixed slots
    uint4*  hA   = (uint4*)alloc((size_t)N * 64 * 2);    // fp16 h', 12.8 MB
    uint4*  hB   = (uint4*)alloc((size_t)N * 64 * 2);
    __half* Wt0h = (__half*)alloc(4096 * 2);             // fp16 W^T, MFMA B operands
    __half* Wt0l = (__half*)alloc(4096 * 2);             // (W0 split hi+lo)
    __half* Wt1  = (__half*)alloc(4096 * 2);
    __half* Wt2  = (__half*)alloc(4096 * 2);

    const int GATH_B = N / 32;               // 3125 (32 nodes/block)

    // pass 1: bucket-sort edges (LDS atomics only); +1 block preps Wt tables
    k_bucket<<<NBLK + 1, 256, 0, stream>>>(src, dst, E, NBLK, arr, scantab,
                                           W0, W1, W2, Wt0h, Wt0l, Wt1, Wt2);
    // pass 2 fused: LDS-staged CSR (coalesced writeout) + deg + gemm0 from
    // LDS counts -> h'0
    k_build0<<<NB, 256, 0, stream>>>(arr, scantab, csr, deg, NBLK, N,
                                     x, Wt0h, Wt0l, (__half*)hA);
    // fused: gather(h'_0) -> y0 -> @W1 (MFMA) -> h'_1
    k_gather_gemm<<<GATH_B, 256, 0, stream>>>(hA, csr, deg, b0, Wt1, (__half*)hB, N);
    // fused: gather(h'_1) -> y1 -> @W2 (MFMA) -> h'_2
    k_gather_gemm<<<GATH_B, 256, 0, stream>>>(hB, csr, deg, b1, Wt2, (__half*)hA, N);
    // final gather -> out (fp32)
    k_gather<<<GATH_B, 256, 0, stream>>>(hA, csr, deg, b2, out, N);
}

// Round 8
// 215.097 us; speedup vs baseline: 1.2412x; 1.0200x over previous
//
#include <hip/hip_runtime.h>
#include <hip/hip_fp16.h>

#define N_NODES 100000
#define CAP 64    // fixed CSR slots per node; deg is Poisson(10), P(>64) ~ 1e-25
#define NB  391   // node buckets of 256 nodes: ceil(100000/256)
#define BE  2048  // edges per pass-1 block

typedef _Float16 v4h __attribute__((ext_vector_type(4)));
typedef float    v4f __attribute__((ext_vector_type(4)));

// ---------------- CSR build (atomic-free two-pass bucket build) ----------------
// Device-scope returning atomics are a ~17-20 G/s coherence-point wall (R1-R5:
// co-residency halves it, nt-hints no help, per-XCD replicas + workgroup scope
// change NOTHING). So: no device atomics anywhere. LDS atomics are banked,
// per-CU, and fast. LDS also eats every scatter; global only ever sees
// coalesced streams (R6/R7 lesson: this is worth ~15-25 us per scattered MB).

// pass 1: per-block bucket sort of 2048 edges into 391 buckets (dst>>8).
// LDS histogram returns local rank; parallel (Hillis-Steele) exclusive scan
// gives bucket starts; edges scatter into LDS lsort (8 KB), then stream out
// coalesced as uint4 into the block's private arr slice, packed uint32
// (dloc<<17 | src). scantab[blk][392] (uint16) = scan row. No overflow
// possible. Positions are a compaction -> [0,tot) dense; lsort tail beyond
// tot is garbage but scantab bounds every later read.
// Last grid block preps fp16 W^T tables instead (MFMA B operands); W0 gets a
// hi+lo split so layer 0 keeps near-fp32 precision.
__global__ __launch_bounds__(256) void k_bucket(
    const int* __restrict__ src, const int* __restrict__ dst, int E, int NBLK,
    unsigned int* __restrict__ arr, unsigned short* __restrict__ scantab,
    const float* __restrict__ W0, const float* __restrict__ W1,
    const float* __restrict__ W2,
    __half* __restrict__ Wt0h, __half* __restrict__ Wt0l,
    __half* __restrict__ Wt1, __half* __restrict__ Wt2) {
    if ((int)blockIdx.x == NBLK) {
        // Wt[c][k] = W[k][c]
        for (int i = threadIdx.x; i < 4096; i += 256) {
            int k = i >> 6, c = i & 63;
            float w0 = W0[i];
            __half w0h = __float2half(w0);
            Wt0h[(c << 6) + k] = w0h;
            Wt0l[(c << 6) + k] = __float2half(w0 - __half2float(w0h));
            Wt1[(c << 6) + k] = __float2half(W1[i]);
            Wt2[(c << 6) + k] = __float2half(W2[i]);
        }
        return;
    }
    __shared__ int cnt[392];   // 391 buckets + 1 pad (never hit) for the scan
    __shared__ int scn[392];
    __shared__ int gs[98];     // 98 groups of 4 for the scan
    __shared__ unsigned int lsort[BE];   // 8 KB staged sorted slice
    int t = threadIdx.x;
    for (int j = t; j < 392; j += 256) cnt[j] = 0;
    __syncthreads();
    int blk = blockIdx.x;
    int base = blk * BE;
    int dsts[8], srcs[8], rnk[8];
#pragma unroll
    for (int i = 0; i < 8; i++) {          // coalesced: e = base + i*256 + t
        int e = base + i * 256 + t;
        int d = (e < E) ? dst[e] : -1;
        srcs[i] = (e < E) ? src[e] : 0;
        dsts[i] = d;
        rnk[i] = (d >= 0) ? atomicAdd(&cnt[d >> 8], 1) : 0;   // LDS atomic
    }
    __syncthreads();
    // exclusive scan of cnt[0..391] -> scn: group sums, Hillis-Steele over 98
    int c0 = 0, c1 = 0, c2 = 0, c3 = 0;
    if (t < 98) {
        c0 = cnt[4 * t]; c1 = cnt[4 * t + 1]; c2 = cnt[4 * t + 2]; c3 = cnt[4 * t + 3];
        gs[t] = c0 + c1 + c2 + c3;
    }
    __syncthreads();
#pragma unroll
    for (int off = 1; off < 128; off <<= 1) {
        int u = (t < 98 && t >= off) ? gs[t - off] : 0;
        __syncthreads();
        if (t < 98) gs[t] += u;
        __syncthreads();
    }
    if (t < 98) {
        int b0 = gs[t] - (c0 + c1 + c2 + c3);   // exclusive group base
        scn[4 * t]     = b0;
        scn[4 * t + 1] = b0 + c0;
        scn[4 * t + 2] = b0 + c0 + c1;
        scn[4 * t + 3] = b0 + c0 + c1 + c2;
    }
    __syncthreads();
    // scatter into LDS (LDS eats it), then coalesced uint4 writeout
#pragma unroll
    for (int i = 0; i < 8; i++) {
        int d = dsts[i];
        if (d >= 0) {
            int pos = scn[d >> 8] + rnk[i];
            lsort[pos] = ((unsigned)(d & 255) << 17) | (unsigned)srcs[i];  // src < 2^17
        }
    }
    __syncthreads();
    uint4* ap = (uint4*)(arr + (size_t)blk * BE);
    const uint4* ls4 = (const uint4*)lsort;
#pragma unroll
    for (int i = 0; i < 2; i++) ap[t + i * 256] = ls4[t + i * 256];
    for (int j = t; j < 392; j += 256)
        scantab[(size_t)blk * 392 + j] = (unsigned short)scn[j];
}

// pass 2 FUSED with gemm0: one block per bucket (256 nodes).
// Phase A: walk the scantab column, LDS-atomic rank over 256 node counters,
//          scatter edges into the bucket's CSR window staged in LDS (64 KB).
// Phase B: stream the window out as coalesced int4 + write deg.
// Phase C: gemm0 for the SAME 256 nodes — h'0 = (x@W0)*dinv — counts straight
//          from LDS cnt (no deg round-trip, no extra launch). A = x hi/lo
//          split, B = W0 hi/lo split -> near-fp32 product (xh*Wh + xl*Wh +
//          xh*Wl; xl*Wl ~ 2^-22 rel). x tiles are DOUBLE-BUFFERED: tile it+1's
//          load issues before tile it's MFMA so HBM latency hides under
//          compute instead of serializing 16x per block.
__global__ __launch_bounds__(256) void k_build0(
    const unsigned int* __restrict__ arr,
    const unsigned short* __restrict__ scantab,
    int* __restrict__ csr, int* __restrict__ deg, int NBLK, int n,
    const float* __restrict__ x,
    const __half* __restrict__ Wth, const __half* __restrict__ Wtl,
    __half* __restrict__ outh) {
    __shared__ int4 lcsr4[4096];          // 64 KB: 256 nodes x 64 slots
    __shared__ int cnt[256];
    __shared__ _Float16 xs_hi[16 * 68];   // stride 68: even bank spread for b64
    __shared__ _Float16 xs_lo[16 * 68];
    int* lcsr = (int*)lcsr4;
    int t = threadIdx.x;
    cnt[t] = 0;
    __syncthreads();
    int b = blockIdx.x;
    int bn = b << 8;
    // ---- phase A: rank + LDS scatter ----
    for (int blk = t; blk < NBLK; blk += 256) {
        int s0 = scantab[(size_t)blk * 392 + b];
        int s1 = scantab[(size_t)blk * 392 + b + 1];
        const unsigned int* a = arr + (size_t)blk * BE;
        for (int k = s0; k < s1; k++) {
            unsigned v = a[k];
            int dloc = (int)(v >> 17);
            int sv = (int)(v & 0x1FFFF);
            int r = atomicAdd(&cnt[dloc], 1);          // LDS atomic
            if (r < CAP) lcsr[(dloc << 6) + r] = sv;
        }
    }
    __syncthreads();
    // ---- phase B: coalesced writeout + deg ----
    int rows = min(256, n - bn);          // last bucket: 160 (multiple of 16)
    int4* cdst = (int4*)(csr + ((size_t)bn << 6));
    for (int i = t; i < rows * 16; i += 256) cdst[i] = lcsr4[i];
    if (bn + t < n) deg[bn + t] = cnt[t];
    // ---- phase C: gemm0 for these nodes, 16 tiles of 16, double-buffered ----
    int rl = t >> 4, q = t & 15;
    int lane = t & 63;
    int w = t >> 6;
    int col = (w << 4) + (lane & 15);
    int g = lane >> 4;
    const v4h* wth4 = (const v4h*)(Wth + ((size_t)col << 6));
    const v4h* wtl4 = (const v4h*)(Wtl + ((size_t)col << 6));
    v4h bfh[4], bfl[4];
#pragma unroll
    for (int s = 0; s < 4; s++) { bfh[s] = wth4[(s << 2) + g]; bfl[s] = wtl4[(s << 2) + g]; }

    int tiles = rows >> 4;
    v4f xv = __builtin_nontemporal_load((const v4f*)x + (size_t)bn * 16 + t);  // tile 0
    for (int it = 0; it < tiles; it++) {
        int nb16 = bn + it * 16;          // tile's first node
        v4h yh = {(_Float16)xv.x, (_Float16)xv.y, (_Float16)xv.z, (_Float16)xv.w};
        v4h yl = {(_Float16)(xv.x - (float)yh.x), (_Float16)(xv.y - (float)yh.y),
                  (_Float16)(xv.z - (float)yh.z), (_Float16)(xv.w - (float)yh.w)};
        *(v4h*)&xs_hi[rl * 68 + (q << 2)] = yh;
        *(v4h*)&xs_lo[rl * 68 + (q << 2)] = yl;
        v4f xn = xv;
        if (it + 1 < tiles)               // prefetch next tile: latency hides
            xn = __builtin_nontemporal_load(                      // under MFMA
                (const v4f*)x + (size_t)(nb16 + 16) * 16 + t);
        __syncthreads();
        v4f acc = {0.f, 0.f, 0.f, 0.f};
        int arow = lane & 15;
#pragma unroll
        for (int s = 0; s < 4; s++) {
            v4h al = *(const v4h*)&xs_lo[arow * 68 + (s << 4) + (g << 2)];
            v4h ah = *(const v4h*)&xs_hi[arow * 68 + (s << 4) + (g << 2)];
            acc = __builtin_amdgcn_mfma_f32_16x16x16f16(al, bfh[s], acc, 0, 0, 0);
            acc = __builtin_amdgcn_mfma_f32_16x16x16f16(ah, bfl[s], acc, 0, 0, 0);
            acc = __builtin_amdgcn_mfma_f32_16x16x16f16(ah, bfh[s], acc, 0, 0, 0);
        }
#pragma unroll
        for (int j = 0; j < 4; j++) {
            int r = (g << 2) + j;
            float dr = rsqrtf((float)(cnt[it * 16 + r] + 1));
            float v = acc[j] * dr;
            outh[((size_t)(nb16 + r) << 6) + col] = __float2half(v);
        }
        __syncthreads();                  // xs reused next tile
        xv = xn;
    }
}

// ---------------- gather helpers (16B-granular) ----------------

// fp16 pairwise add of two gathered uint4s (8 halves): 4x v_pk_add_f16.
// Exactly ONE fp16 rounding per element (passed at 4.88e-4 total).
__device__ __forceinline__ uint4 padd4(uint4 u, uint4 v) {
    __half2* a = (__half2*)&u;
    __half2* b = (__half2*)&v;
    uint4 r;
    __half2* c = (__half2*)&r;
#pragma unroll
    for (int k = 0; k < 4; k++) c[k] = __hadd2(a[k], b[k]);
    return r;
}

// fp32 accumulate of 8 halves into two v4f
__device__ __forceinline__ void acc_h4(v4f& A, v4f& B, uint4 v) {
    __half2* h = (__half2*)&v;
    float2 f0 = __half22float2(h[0]);
    float2 f1 = __half22float2(h[1]);
    float2 f2 = __half22float2(h[2]);
    float2 f3 = __half22float2(h[3]);
    v4f fa = {f0.x, f0.y, f1.x, f1.y};
    v4f fb = {f2.x, f2.y, f3.x, f3.y};
    A = A + fa;
    B = B + fb;
}

// yA/yB = 8 columns of h'[node] + sum_j h'[j]; fp32 master acc, one fp16
// pairing level. 16B loads (uint4, 8 lanes/node). Caller pre-loads ia=c4[0],
// ib=c4[1] BEFORE the deg load so the deg->idx->gather chain collapses to one
// hop. Prefetched idx entries may read up to 28 B past the node's row
// (in-allocation) and are only USED when the count checks validate them.
__device__ __forceinline__ void gather_acc4(const uint4* __restrict__ h4,
                                            const int* __restrict__ csr,
                                            int4 ia, int4 ib,
                                            int node, int qq, int cnt,
                                            v4f& yA, v4f& yB) {
    const int4* c4 = (const int4*)(csr + (node << 6));
    v4f A0 = {0,0,0,0}, A1 = {0,0,0,0}, A2 = {0,0,0,0}, A3 = {0,0,0,0};
    v4f B0 = {0,0,0,0}, B1 = {0,0,0,0}, B2 = {0,0,0,0}, B3 = {0,0,0,0};
    acc_h4(A0, B0, h4[(size_t)node * 8 + qq]);  // self loop (fp32 path)
    int e = 0;
    for (; e + 8 <= cnt; ) {
        uint4 v0 = h4[(size_t)ia.x * 8 + qq];
        uint4 v1 = h4[(size_t)ia.y * 8 + qq];
        uint4 v2 = h4[(size_t)ia.z * 8 + qq];
        uint4 v3 = h4[(size_t)ia.w * 8 + qq];
        uint4 v4 = h4[(size_t)ib.x * 8 + qq];
        uint4 v5 = h4[(size_t)ib.y * 8 + qq];
        uint4 v6 = h4[(size_t)ib.z * 8 + qq];
        uint4 v7 = h4[(size_t)ib.w * 8 + qq];
        e += 8;
        ia = c4[e >> 2];            // prefetch overlaps the accumulate VALU below
        ib = c4[(e >> 2) + 1];
        uint4 p0 = padd4(v0, v1);
        uint4 p1 = padd4(v2, v3);
        uint4 p2 = padd4(v4, v5);
        uint4 p3 = padd4(v6, v7);
        acc_h4(A0, B0, p0); acc_h4(A1, B1, p1);
        acc_h4(A2, B2, p2); acc_h4(A3, B3, p3);
    }
    if (e + 4 <= cnt) {
        uint4 v0 = h4[(size_t)ia.x * 8 + qq];
        uint4 v1 = h4[(size_t)ia.y * 8 + qq];
        uint4 v2 = h4[(size_t)ia.z * 8 + qq];
        uint4 v3 = h4[(size_t)ia.w * 8 + qq];
        uint4 p0 = padd4(v0, v1);
        uint4 p1 = padd4(v2, v3);
        acc_h4(A1, B1, p0); acc_h4(A2, B2, p1);
        e += 4;
        ia = ib;                    // keep invariant ia = c4[e/4]
    }
    int rem = cnt - e;              // 0..3, one masked parallel iteration (fp32)
    if (rem > 0) {
        int j0 = ia.x;              // slot e < cnt -> valid
        int j1 = (rem > 1) ? ia.y : j0;
        int j2 = (rem > 2) ? ia.z : j0;
        uint4 v0 = h4[(size_t)j0 * 8 + qq];
        uint4 v1 = h4[(size_t)j1 * 8 + qq];
        uint4 v2 = h4[(size_t)j2 * 8 + qq];
        acc_h4(A1, B1, v0);
        if (rem > 1) acc_h4(A2, B2, v1);
        if (rem > 2) acc_h4(A3, B3, v2);
    }
    yA = (A0 + A1) + (A2 + A3);
    yB = (B0 + B1) + (B2 + B3);
}

// Fused interior layer, 32 nodes/block (8 lanes x 16B per node):
// y = relu(dinv_i*(gather h'_l) + b_l) -> h'_{l+1} = (y @ W_{l+1})*dinv_i.
// GEMM on MFMA: A = y split hi/lo fp16, B = Wt fp16 from global (L2-hot).
// Per wave: two 16x16 out tiles (rows 0-15 / 16-31), 16 MFMAs.
__global__ __launch_bounds__(256) void k_gather_gemm(const uint4* __restrict__ h4,
                                                     const int* __restrict__ csr,
                                                     const int* __restrict__ deg,
                                                     const float* __restrict__ bias,
                                                     const __half* __restrict__ Wt,
                                                     __half* __restrict__ outh, int n) {
    // row stride 68 halves (34 dwords ≡ 2 mod 32): b64 reads spread all banks
    __shared__ _Float16 xs_hi[32 * 68];
    __shared__ _Float16 xs_lo[32 * 68];
    __shared__ float dsv[32];
    (void)n;
    int t = threadIdx.x;
    int nl = t >> 3, qq = t & 7;     // 32 nodes/block, 8 lanes/node
    int node = blockIdx.x * 32 + nl;
    int lane = t & 63;
    int w = t >> 6;                  // wave id 0..3 -> out-col tile
    int col = (w << 4) + (lane & 15);
    int g = lane >> 4;               // k-subgroup within fragment

    const int4* c4 = (const int4*)(csr + (node << 6));
    int4 ia0 = c4[0];                // idx hoist: overlaps the deg load
    int4 ib0 = c4[1];
    int dg = deg[node];
    int cnt = min(dg, CAP);
    float d_i = rsqrtf((float)(dg + 1));
    if (qq == 0) dsv[nl] = d_i;
    float4 bA = ((const float4*)bias)[qq * 2 + 0];
    float4 bB = ((const float4*)bias)[qq * 2 + 1];

    v4f aA, aB;
    gather_acc4(h4, csr, ia0, ib0, node, qq, cnt, aA, aB);

    // B fragments (lane: B[k][j], j -> col, k=16s+4g..+3): issue now, latency
    // hides under relu/convert/LDS-write/barrier.
    const v4h* wt4 = (const v4h*)(Wt + ((size_t)col << 6));
    v4h bf[4];
#pragma unroll
    for (int s = 0; s < 4; s++) bf[s] = wt4[(s << 2) + g];

    float y0 = fmaxf(fmaf(aA.x, d_i, bA.x), 0.f);
    float y1 = fmaxf(fmaf(aA.y, d_i, bA.y), 0.f);
    float y2 = fmaxf(fmaf(aA.z, d_i, bA.z), 0.f);
    float y3 = fmaxf(fmaf(aA.w, d_i, bA.w), 0.f);
    float y4 = fmaxf(fmaf(aB.x, d_i, bB.x), 0.f);
    float y5 = fmaxf(fmaf(aB.y, d_i, bB.y), 0.f);
    float y6 = fmaxf(fmaf(aB.z, d_i, bB.z), 0.f);
    float y7 = fmaxf(fmaf(aB.w, d_i, bB.w), 0.f);
    v4h yhA = {(_Float16)y0, (_Float16)y1, (_Float16)y2, (_Float16)y3};
    v4h ylA = {(_Float16)(y0 - (float)yhA.x), (_Float16)(y1 - (float)yhA.y),
               (_Float16)(y2 - (float)yhA.z), (_Float16)(y3 - (float)yhA.w)};
    v4h yhB = {(_Float16)y4, (_Float16)y5, (_Float16)y6, (_Float16)y7};
    v4h ylB = {(_Float16)(y4 - (float)yhB.x), (_Float16)(y5 - (float)yhB.y),
               (_Float16)(y6 - (float)yhB.z), (_Float16)(y7 - (float)yhB.w)};
    *(v4h*)&xs_hi[nl * 68 + (qq << 3) + 0] = yhA;
    *(v4h*)&xs_hi[nl * 68 + (qq << 3) + 4] = yhB;
    *(v4h*)&xs_lo[nl * 68 + (qq << 3) + 0] = ylA;
    *(v4h*)&xs_lo[nl * 68 + (qq << 3) + 4] = ylB;
    __syncthreads();

    // two row-tiles per wave: rows 0-15 and 16-31
    v4f acc0 = {0.f, 0.f, 0.f, 0.f};
    v4f acc1 = {0.f, 0.f, 0.f, 0.f};
    int ar = lane & 15;              // A: row = ar (+16), k = 16s + 4g + 0..3
#pragma unroll
    for (int s = 0; s < 4; s++) {
        int ko = (s << 4) + (g << 2);
        v4h al0 = *(const v4h*)&xs_lo[ar * 68 + ko];
        v4h ah0 = *(const v4h*)&xs_hi[ar * 68 + ko];
        v4h al1 = *(const v4h*)&xs_lo[(ar + 16) * 68 + ko];
        v4h ah1 = *(const v4h*)&xs_hi[(ar + 16) * 68 + ko];
        acc0 = __builtin_amdgcn_mfma_f32_16x16x16f16(al0, bf[s], acc0, 0, 0, 0);
        acc0 = __builtin_amdgcn_mfma_f32_16x16x16f16(ah0, bf[s], acc0, 0, 0, 0);
        acc1 = __builtin_amdgcn_mfma_f32_16x16x16f16(al1, bf[s], acc1, 0, 0, 0);
        acc1 = __builtin_amdgcn_mfma_f32_16x16x16f16(ah1, bf[s], acc1, 0, 0, 0);
    }

    // D: col = lane&15 (-> global col), row = 4g + j (+16 for tile 1). Scale
    // by the OUTPUT row's dinv (LDS, written pre-barrier), store fp16.
#pragma unroll
    for (int j = 0; j < 4; j++) {
        int r0 = (g << 2) + j;
        float v0 = acc0[j] * dsv[r0];
        outh[((size_t)(blockIdx.x * 32 + r0) << 6) + col] = __float2half(v0);
        int r1 = r0 + 16;
        float v1 = acc1[j] * dsv[r1];
        outh[((size_t)(blockIdx.x * 32 + r1) << 6) + col] = __float2half(v1);
    }
}

// Final gather, 32 nodes/block: out = relu(dinv_i*(gather h'_2) + b2), fp32.
__global__ __launch_bounds__(256) void k_gather(const uint4* __restrict__ h4,
                                                const int* __restrict__ csr,
                                                const int* __restrict__ deg,
                                                const float* __restrict__ bias,
                                                float* __restrict__ out, int n) {
    int t = threadIdx.x;
    int nl = t >> 3, qq = t & 7;
    int node = blockIdx.x * 32 + nl;
    if (node >= n) return;
    const int4* c4 = (const int4*)(csr + (node << 6));
    int4 ia0 = c4[0];                // idx hoist (see gather_acc4)
    int4 ib0 = c4[1];
    int dg = deg[node];
    int cnt = min(dg, CAP);
    float d = rsqrtf((float)(dg + 1));
    v4f aA, aB;
    gather_acc4(h4, csr, ia0, ib0, node, qq, cnt, aA, aB);
    float4 bA = ((const float4*)bias)[qq * 2 + 0];
    float4 bB = ((const float4*)bias)[qq * 2 + 1];
    float4 rA, rB;
    rA.x = fmaxf(fmaf(aA.x, d, bA.x), 0.f);
    rA.y = fmaxf(fmaf(aA.y, d, bA.y), 0.f);
    rA.z = fmaxf(fmaf(aA.z, d, bA.z), 0.f);
    rA.w = fmaxf(fmaf(aA.w, d, bA.w), 0.f);
    rB.x = fmaxf(fmaf(aB.x, d, bB.x), 0.f);
    rB.y = fmaxf(fmaf(aB.y, d, bB.y), 0.f);
    rB.z = fmaxf(fmaf(aB.z, d, bB.z), 0.f);
    rB.w = fmaxf(fmaf(aB.w, d, bB.w), 0.f);
    ((float4*)out)[(size_t)node * 16 + qq * 2 + 0] = rA;
    ((float4*)out)[(size_t)node * 16 + qq * 2 + 1] = rB;
}

// ---------------- launch ----------------

extern "C" void kernel_launch(void* const* d_in, const int* in_sizes, int n_in,
                              void* d_out, int out_size, void* d_ws, size_t ws_size,
                              hipStream_t stream) {
    const float* x  = (const float*)d_in[0];
    const int*   ei = (const int*)d_in[1];
    const float* W0 = (const float*)d_in[2];
    const float* b0 = (const float*)d_in[3];
    const float* W1 = (const float*)d_in[4];
    const float* b1 = (const float*)d_in[5];
    const float* W2 = (const float*)d_in[6];
    const float* b2 = (const float*)d_in[7];
    float* out = (float*)d_out;

    const int N = N_NODES;
    int E = in_sizes[1] / 2;
    const int* src = ei;
    const int* dst = ei + E;
    const int NBLK = (E + BE - 1) / BE;      // pass-1 blocks

    char* p = (char*)d_ws;
    auto alloc = [&](size_t bytes) -> void* {
        void* r = (void*)p;
        p += (bytes + 511) & ~(size_t)511;
        return r;
    };
    int*    deg  = (int*)alloc((size_t)N * 4);
    unsigned int*   arr     = (unsigned int*)alloc((size_t)NBLK * BE * 4);   // ~4 MB
    unsigned short* scantab = (unsigned short*)alloc((size_t)NBLK * 392 * 2);// ~0.4 MB
    int*    csr  = (int*)alloc((size_t)N * CAP * 4);     // 25.6 MB fixed slots
    uint4*  hA   = (uint4*)alloc((size_t)N * 64 * 2);    // fp16 h', 12.8 MB
    uint4*  hB   = (uint4*)alloc((size_t)N * 64 * 2);
    __half* Wt0h = (__half*)alloc(4096 * 2);             // fp16 W^T, MFMA B operands
    __half* Wt0l = (__half*)alloc(4096 * 2);             // (W0 split hi+lo)
    __half* Wt1  = (__half*)alloc(4096 * 2);
    __half* Wt2  = (__half*)alloc(4096 * 2);

    const int GATH_B = N / 32;               // 3125 (32 nodes/block)

    // pass 1: bucket-sort edges (LDS atomics, LDS-staged coalesced writeout);
    // +1 block preps Wt tables
    k_bucket<<<NBLK + 1, 256, 0, stream>>>(src, dst, E, NBLK, arr, scantab,
                                           W0, W1, W2, Wt0h, Wt0l, Wt1, Wt2);
    // pass 2 fused: LDS-staged CSR (coalesced writeout) + deg + gemm0 from
    // LDS counts (double-buffered x tiles) -> h'0
    k_build0<<<NB, 256, 0, stream>>>(arr, scantab, csr, deg, NBLK, N,
                                     x, Wt0h, Wt0l, (__half*)hA);
    // fused: gather(h'_0) -> y0 -> @W1 (MFMA) -> h'_1
    k_gather_gemm<<<GATH_B, 256, 0, stream>>>(hA, csr, deg, b0, Wt1, (__half*)hB, N);
    // fused: gather(h'_1) -> y1 -> @W2 (MFMA) -> h'_2
    k_gather_gemm<<<GATH_B, 256, 0, stream>>>(hB, csr, deg, b1, Wt2, (__half*)hA, N);
    // final gather -> out (fp32)
    k_gather<<<GATH_B, 256, 0, stream>>>(hA, csr, deg, b2, out, N);
}